// Round 4
// baseline (755.507 us; speedup 1.0000x reference)
//
#include <hip/hip_runtime.h>
#include <hip/hip_bf16.h>

// Problem constants (B,S,N,F,H,E) = (4,8,4000,64,128,32000)
#define B_  4
#define S_  8
#define N_  4000
#define F_  64
#define H_  128
#define E_  32000
#define G_  (B_*S_)        // 32 graphs
#define GN_ (G_*N_)        // 128000 node rows
#define M_  (B_*N_)        // 16000 LSTM rows
#define GE_ (G_*E_)        // 1,024,000 edges total
#define HALF_GN 64000
#define HALF_M  8000

// f32 weight scratch offsets (floats)
#define OFF_W0S 0
#define OFF_B0S 8192
#define OFF_W0D 8320
#define OFF_B0D 16512
#define OFF_W1S 16640
#define OFF_B1S 33024
#define OFF_W1D 33152
#define OFF_B1D 49536
#define OFF_WIH 49664
#define OFF_WHH 115200
#define OFF_BIH 180736
#define OFF_BHH 181248
#define OFF_WP  181760
#define OFF_BP  189952
#define WCV_TOTAL 190016

// workspace layout (float offsets)
#define WS_FLAG   0
#define WS_WCV    16
#define WS_WPH    190032      // Whh bf16 [512][128]: 65536 ushorts
#define WS_WPC    222800      // composed Wc bf16 [512][256]: 131072 ushorts
#define WS_BIASC  288336      // 512 f32
#define WS_DEGO   288848      // deg_o, deg_i, cnt_i, cnt_o contiguous: 4 x 128000 words
#define WS_DEGI   416848
#define WS_CNTI   544848
#define WS_CNTO   672848
#define WS_RPI    800848      // 32*4001
#define WS_RPO    928880
#define WS_CURI   1056912
#define WS_CURO   1184912
#define WS_CSRI   1312912     // int2 x GE
#define WS_CSRO   3360912
#define WS_X2     5408912     // [GN][256] bf16; first 8.2M ushorts alias Xb [GN][64] bf16
#define WS_HB     21792912    // [GN][128] bf16
#define WS_GT     29984912    // gates half [64000][512] bf16; aliases PQ0 bf16 [GN][128]
#define WS_WC0    46368912    // Wc0 bf16 [128][128]: 16384 ushorts = 8192 floats
// end: 46,377,104 floats = 185.5 MiB (proven budget >= 193 MiB)

typedef __attribute__((ext_vector_type(8))) short bf16x8;
typedef __attribute__((ext_vector_type(4))) float f32x4;
typedef __attribute__((ext_vector_type(8))) unsigned short ushort8;

__device__ inline float bfu2f(unsigned short u){ union{unsigned int i; float f;} v; v.i=((unsigned int)u)<<16; return v.f; }
__device__ inline unsigned short f2bfu(float f){ __hip_bfloat16 b = __float2bfloat16(f); return *(unsigned short*)&b; }
__device__ inline float rcpf(float x){ return __builtin_amdgcn_rcpf(x); }
__device__ inline float sigmf(float x){ return rcpf(1.0f + __expf(-x)); }
__device__ inline float tanhfast(float x){ return 1.0f - 2.0f*rcpf(1.0f + __expf(2.0f*x)); }
__device__ inline float loadf(const void* p, long i, int isf32){
    return isf32 ? ((const float*)p)[i]
                 : __bfloat162float(((const __hip_bfloat16*)p)[i]);
}
__device__ inline float4 cvtbf4(ushort4 u){
    float4 f;
    f.x = __uint_as_float(((unsigned)u.x)<<16);
    f.y = __uint_as_float(((unsigned)u.y)<<16);
    f.z = __uint_as_float(((unsigned)u.z)<<16);
    f.w = __uint_as_float(((unsigned)u.w)<<16);
    return f;
}

// ---------------- dtype sniff (inputs f32 vs bf16) ----------------
__global__ void sniff_kernel(const unsigned int* __restrict__ ew, int* __restrict__ flag){
    __shared__ int s;
    if (threadIdx.x == 0) s = 0;
    __syncthreads();
    unsigned int lo = ew[threadIdx.x] & 0xFFFFu;
    if (lo > 0x3F80u) atomicOr(&s, 1);
    __syncthreads();
    if (threadIdx.x == 0) flag[0] = s;   // 1 => inputs are f32
}

// ---------------- zero deg/cnt arrays (contiguous 4 x 128000 words) ----------------
__global__ void zero4_kernel(float* __restrict__ p){
    int idx = blockIdx.x*256 + threadIdx.x;
    if (idx < 4*GN_) p[idx] = 0.f;
}

// ---------------- weight conversion to f32 scratch ----------------
struct WSeg { const void* src; int base; int n; };
struct WDesc { WSeg seg[14]; };
__global__ void convert_weights(WDesc d, float* __restrict__ dst, const int* __restrict__ flag){
    int isf32 = flag[0];
    int idx = blockIdx.x*256 + threadIdx.x;
    #pragma unroll
    for (int s=0;s<14;s++){
        int off = idx - d.seg[s].base;
        if (off >= 0 && off < d.seg[s].n){
            dst[idx] = loadf(d.seg[s].src, off, isf32);
            return;
        }
    }
}

// ---------------- Whh bf16 copy ----------------
__global__ void repack_whh(const float* __restrict__ wcv, unsigned short* __restrict__ whb){
    int idx = blockIdx.x*256 + threadIdx.x;   // < 65536
    whb[idx] = f2bfu(wcv[OFF_WHH + idx]);
}

// ---------------- layer-0 composed weights: Wc0[n][k] bf16 [128][128] ----------------
// k<64: 0.5*W0s[n][k] ; k>=64: 0.5*W0d[n][k-64]
__global__ void repack_wc0(const float* __restrict__ wcv, unsigned short* __restrict__ wc0){
    int idx = blockIdx.x*256 + threadIdx.x;   // < 16384
    int k = idx & 127, n = idx >> 7;
    float v = (k < 64) ? 0.5f*wcv[OFF_W0S + n*64 + k] : 0.5f*wcv[OFF_W0D + n*64 + (k-64)];
    wc0[idx] = f2bfu(v);
}

// ---------------- x_seq -> bf16 Xb [GN][64] ----------------
__global__ void xcvt_kernel(const void* __restrict__ x, const int* __restrict__ flag,
                            unsigned short* __restrict__ Xb){
    long idx = (long)blockIdx.x*256 + threadIdx.x;
    if (idx >= (long)GN_*64) return;
    Xb[idx] = f2bfu(loadf(x, idx, flag[0]));
}

// ---------------- composed weights: Wc[n][k] bf16 [512][256] ----------------
__global__ __launch_bounds__(256) void compose_wc(const float* __restrict__ wcv,
                                                  unsigned short* __restrict__ wpc){
    int n = blockIdx.x;        // 512 blocks
    int k = threadIdx.x;       // 256
    const float* wih = wcv + OFF_WIH + n*128;
    const float* w1  = (k < 128) ? (wcv + OFF_W1S + k) : (wcv + OFF_W1D + (k-128));
    float s = 0.f;
    for (int h=0; h<128; h++) s += wih[h] * w1[h*128];
    wpc[n*256 + k] = f2bfu(0.5f * s);
}

// biasc[n] = bih[n]+bhh[n] + sum_h Wih[n][h]*0.5*(b1s[h]+b1d[h])
__global__ void compose_bias(const float* __restrict__ wcv, float* __restrict__ biasc){
    int n = blockIdx.x*256 + threadIdx.x;
    if (n >= 512) return;
    float s = wcv[OFF_BIH+n] + wcv[OFF_BHH+n];
    const float* wih = wcv + OFF_WIH + n*128;
    for (int h=0; h<128; h++) s += wih[h] * 0.5f*(wcv[OFF_B1S+h] + wcv[OFF_B1D+h]);
    biasc[n] = s;
}

// ---------------- per-graph histogram: weighted degrees + counts ----------------
// R4: replace 32-block LDS-atomic version (5.4% occupancy, latency-bound, 89us) with
// full-width global atomics, XCD-swizzled like fill: per-XCD footprint = 4 graphs x
// 4 arrays x 16KB = 256KB, L2-resident; avg contention 8 adds/counter.
__global__ __launch_bounds__(256) void hist_kernel(
        const int* __restrict__ ei, const void* __restrict__ ew, const int* __restrict__ flag,
        float* __restrict__ deg_o, float* __restrict__ deg_i,
        int* __restrict__ cnt_in, int* __restrict__ cnt_out){
    int xcd   = blockIdx.x & 7;
    int rest  = blockIdx.x >> 3;           // 0..499
    int g     = xcd*4 + (rest & 3);        // wave-uniform graph
    int chunk = rest >> 2;                 // 0..124
    int e     = chunk*256 + threadIdx.x;   // 0..31999
    int isf32 = flag[0];
    const int* eib = ei + g*2*E_;
    int s = eib[e], d = eib[E_+e];
    float w = loadf(ew, (long)g*E_+e, isf32);
    atomicAdd(&deg_o[g*N_+s], w);
    atomicAdd(&deg_i[g*N_+d], w);
    atomicAdd(&cnt_out[g*N_+s], 1);
    atomicAdd(&cnt_in[g*N_+d], 1);
}

// ---------------- exclusive scan -> row_ptr + cursors ----------------
__global__ __launch_bounds__(256) void scan_kernel(
        const int* __restrict__ cnt_in, const int* __restrict__ cnt_out,
        int* __restrict__ rp_in, int* __restrict__ rp_out,
        int* __restrict__ cur_in, int* __restrict__ cur_out){
    __shared__ int part[256], pref[256];
    int g = blockIdx.x & 31, dir = blockIdx.x >> 5;
    const int* cnt = (dir ? cnt_out : cnt_in) + g*N_;
    int* rp  = (dir ? rp_out  : rp_in)  + g*(N_+1);
    int* cur = (dir ? cur_out : cur_in) + g*N_;
    int tid = threadIdx.x, base = tid*16;
    int sum = 0;
    for (int i=0;i<16;i++){ int p = base+i; if (p < N_) sum += cnt[p]; }
    part[tid] = sum;
    __syncthreads();
    if (tid == 0){ int run = 0; for (int j=0;j<256;j++){ pref[j] = run; run += part[j]; } }
    __syncthreads();
    int run = pref[tid];
    for (int i=0;i<16;i++){
        int p = base+i;
        if (p < N_){ rp[p] = run; cur[p] = run; run += cnt[p]; }
    }
    if (tid == 255) rp[N_] = run;
}

// ---------------- fill CSR ----------------
// R3: XCD-swizzled so each XCD's scatter footprint is 4 graphs x 2 dirs x 256KB = 2MB < 4MB L2.
// CSR lines then stay L2-resident until all 8 int2 entries of a 64B line land -> full-line
// writebacks instead of ~8x write amplification. Swizzle is perf-only (atomics device-scope).
__global__ __launch_bounds__(256) void fill_kernel(
        const int* __restrict__ ei, const void* __restrict__ ew,
        const int* __restrict__ flag,
        const float* __restrict__ deg_o, const float* __restrict__ deg_i,
        int* __restrict__ cur_in, int* __restrict__ cur_out,
        int2* __restrict__ csr_in, int2* __restrict__ csr_out){
    int xcd   = blockIdx.x & 7;
    int rest  = blockIdx.x >> 3;           // 0..499
    int g     = xcd*4 + (rest & 3);        // wave-uniform graph
    int chunk = rest >> 2;                 // 0..124
    int e     = chunk*256 + threadIdx.x;   // 0..31999
    int isf32 = flag[0];
    const int* eib = ei + g*2*E_;
    int s = eib[e], d = eib[E_ + e];
    float dout = deg_o[g*N_+s], din = deg_i[g*N_+d];
    float io = dout > 0.f ? rsqrtf(fmaxf(dout, 1e-12f)) : 0.f;
    float ii = din  > 0.f ? rsqrtf(fmaxf(din , 1e-12f)) : 0.f;
    float nrm = loadf(ew, (long)g*E_ + e, isf32) * io * ii;
    int p1 = atomicAdd(&cur_in[g*N_+d], 1);
    csr_in[(long)g*E_ + p1] = make_int2(s, __float_as_int(nrm));
    int p2 = atomicAdd(&cur_out[g*N_+s], 1);
    csr_out[(long)g*E_ + p2] = make_int2(d, __float_as_int(nrm));
}

// ---------------- gather layer 0 -> PQ0 bf16 [GN][128] (dir0 cols 0..63, dir1 64..127) ----------------
// R2: 8 nodes per wave, ushort8 (16B) per lane, 8 lanes cover a 64-col row.
// csr entry + address math + mask amortized per 8-lane group; scalar row base (g uniform).
__global__ __launch_bounds__(256) void gather64(
        const int* __restrict__ rp_in, const int* __restrict__ rp_out,
        const int2* __restrict__ csr_in, const int2* __restrict__ csr_out,
        const unsigned short* __restrict__ Xb,
        unsigned short* __restrict__ PQ0){
    int xcd  = blockIdx.x & 7;
    int rest = blockIdx.x >> 3;            // 0..999
    int g    = xcd*4 + (rest & 3);         // wave-uniform
    int chunk= rest >> 2;                  // 0..249
    int wave = threadIdx.x >> 6;
    int lane = threadIdx.x & 63;
    int sub  = lane >> 3;                  // node slot 0..7
    int li   = lane & 7;                   // col group (8 bf16 each)
    int wl   = chunk*32 + wave*8 + sub;    // 0..7999
    int dir  = wl >= N_;  int n = wl - dir*N_;
    const int*  rp  = (dir ? rp_out : rp_in) + g*(N_+1);
    const int2* csr = (dir ? csr_out : csr_in) + (long)g*E_;
    int pb = rp[n], pe = rp[n+1];
    int plast = max(pe - 1, 0);
    const unsigned short* base = Xb + (size_t)g*N_*64;   // scalar base
    float acc[8];
    #pragma unroll
    for (int j=0;j<8;j++) acc[j] = 0.f;
    for (int p = pb; __any(p < pe); p += 4){
        float w[4]; ushort8 v[4];
        #pragma unroll
        for (int i=0;i<4;i++){
            int pi = p+i;
            int2 ent = csr[min(pi, plast)];
            w[i] = (pi < pe) ? __int_as_float(ent.y) : 0.f;
            v[i] = *(const ushort8*)(base + ent.x*64 + li*8);
        }
        #pragma unroll
        for (int i=0;i<4;i++)
            #pragma unroll
            for (int j=0;j<8;j++)
                acc[j] += w[i]*bfu2f(v[i][j]);
    }
    ushort8 o;
    #pragma unroll
    for (int j=0;j<8;j++) o[j] = f2bfu(acc[j]);
    *(ushort8*)(PQ0 + (size_t)(g*N_+n)*128 + dir*64 + li*8) = o;
}

// ---------------- gather layer 1 -> X2 bf16 [GN][256] (XCD-swizzled) ----------------
// R2: 4 nodes per wave, ushort8 per lane, 16 lanes cover a 128-col row.
__global__ __launch_bounds__(256) void gather128(
        const int* __restrict__ rp_in, const int* __restrict__ rp_out,
        const int2* __restrict__ csr_in, const int2* __restrict__ csr_out,
        const unsigned short* __restrict__ hb,
        unsigned short* __restrict__ X2){
    int xcd  = blockIdx.x & 7;
    int rest = blockIdx.x >> 3;            // 0..1999
    int g    = xcd*4 + (rest & 3);         // wave-uniform
    int chunk= rest >> 2;                  // 0..499
    int wave = threadIdx.x >> 6;
    int lane = threadIdx.x & 63;
    int sub  = lane >> 4;                  // node slot 0..3
    int li   = lane & 15;                  // col group (8 bf16 each)
    int wl   = chunk*16 + wave*4 + sub;    // 0..7999
    int dir  = wl >= N_;  int n = wl - dir*N_;
    const int*  rp  = (dir ? rp_out : rp_in) + g*(N_+1);
    const int2* csr = (dir ? csr_out : csr_in) + (long)g*E_;
    int pb = rp[n], pe = rp[n+1];
    int plast = max(pe - 1, 0);
    const unsigned short* base = hb + (size_t)g*N_*128;  // scalar base
    float acc[8];
    #pragma unroll
    for (int j=0;j<8;j++) acc[j] = 0.f;
    for (int p = pb; __any(p < pe); p += 4){
        float w[4]; ushort8 v[4];
        #pragma unroll
        for (int i=0;i<4;i++){
            int pi = p+i;
            int2 ent = csr[min(pi, plast)];
            w[i] = (pi < pe) ? __int_as_float(ent.y) : 0.f;
            v[i] = *(const ushort8*)(base + ent.x*128 + li*8);
        }
        #pragma unroll
        for (int i=0;i<4;i++)
            #pragma unroll
            for (int j=0;j<8;j++)
                acc[j] += w[i]*bfu2f(v[i][j]);
    }
    ushort8 o;
    #pragma unroll
    for (int j=0;j<8;j++) o[j] = f2bfu(acc[j]);
    *(ushort8*)(X2 + (size_t)(g*N_+n)*256 + dir*128 + li*8) = o;
}

// ---------------- MFMA layer-0 GEMM: Hb[GN][128] = PQ0 @ Wc0^T + 0.5(b0s+b0d) ----------------
// same tile structure as gemmg, K=128 (4 ks-chunks), 2 col-tiles of 64.
__global__ __launch_bounds__(256) void gemm0(
        const unsigned short* __restrict__ PQ0, const unsigned short* __restrict__ wc0,
        const float* __restrict__ wcv, __hip_bfloat16* __restrict__ Hb){
    __shared__ unsigned short As[2][64*40];
    int tid  = threadIdx.x;
    int wave = tid >> 6, lane = tid & 63;
    int quad = lane >> 4, l16 = lane & 15;
    int nb = blockIdx.x & 1, mb = blockIdx.x >> 1;
    int m0 = mb*64;
    int col = nb*64 + wave*16 + l16;
    bf16x8 bq[4];
    #pragma unroll
    for (int ks=0; ks<4; ks++)
        bq[ks] = *(const bf16x8*)(wc0 + (size_t)col*128 + ks*32 + quad*8);
    f32x4 acc[4];
    #pragma unroll
    for (int t=0;t<4;t++) acc[t] = (f32x4){0.f,0.f,0.f,0.f};
    int srow = tid>>2, sch = tid&3;
    const unsigned short* src_base = PQ0 + (size_t)(m0 + srow)*128 + sch*8;
    *(float4*)(&As[0][srow*40 + sch*8]) = *(const float4*)(src_base);
    __syncthreads();
    for (int ks=0; ks<4; ks++){
        if (ks < 3)
            *(float4*)(&As[(ks+1)&1][srow*40 + sch*8]) = *(const float4*)(src_base + (ks+1)*32);
        const unsigned short* ab = As[ks&1];
        #pragma unroll
        for (int t=0;t<4;t++){
            bf16x8 a = *(const bf16x8*)(ab + (t*16 + l16)*40 + quad*8);
            acc[t] = __builtin_amdgcn_mfma_f32_16x16x32_bf16(a, bq[ks], acc[t], 0, 0, 0);
        }
        __syncthreads();
    }
    float bias = 0.5f*(wcv[OFF_B0S+col] + wcv[OFF_B0D+col]);
    #pragma unroll
    for (int t=0;t<4;t++){
        #pragma unroll
        for (int r=0;r<4;r++){
            int grow = m0 + t*16 + quad*4 + r;
            Hb[(size_t)grow*128 + col] = __float2bfloat16(acc[t][r] + bias);
        }
    }
}

// ---------------- MFMA gates GEMM: gates[64000][512] = X2 @ Wc^T + biasc ----------------
__global__ __launch_bounds__(256) void gemmg(
        const unsigned short* __restrict__ X2, const unsigned short* __restrict__ wpc,
        const float* __restrict__ biasc, unsigned short* __restrict__ gates, int gn_base){
    __shared__ unsigned short As[2][64*40];
    int tid  = threadIdx.x;
    int wave = tid >> 6, lane = tid & 63;
    int quad = lane >> 4, l16 = lane & 15;
    int nb = blockIdx.x & 7, mb = blockIdx.x >> 3;
    int m0 = mb*64;
    int col = nb*64 + wave*16 + l16;
    bf16x8 bq[8];
    #pragma unroll
    for (int ks=0; ks<8; ks++)
        bq[ks] = *(const bf16x8*)(wpc + (size_t)col*256 + ks*32 + quad*8);
    f32x4 acc[4];
    #pragma unroll
    for (int t=0;t<4;t++) acc[t] = (f32x4){0.f,0.f,0.f,0.f};
    int srow = tid>>2, sch = tid&3;
    const unsigned short* src_base = X2 + (size_t)(gn_base + m0 + srow)*256 + sch*8;
    *(float4*)(&As[0][srow*40 + sch*8]) = *(const float4*)(src_base);
    __syncthreads();
    for (int ks=0; ks<8; ks++){
        if (ks < 7)
            *(float4*)(&As[(ks+1)&1][srow*40 + sch*8]) = *(const float4*)(src_base + (ks+1)*32);
        const unsigned short* ab = As[ks&1];
        #pragma unroll
        for (int t=0;t<4;t++){
            bf16x8 a = *(const bf16x8*)(ab + (t*16 + l16)*40 + quad*8);
            acc[t] = __builtin_amdgcn_mfma_f32_16x16x32_bf16(a, bq[ks], acc[t], 0, 0, 0);
        }
        __syncthreads();
    }
    float bc = biasc[col];
    #pragma unroll
    for (int t=0;t<4;t++){
        #pragma unroll
        for (int r=0;r<4;r++){
            int grow = m0 + t*16 + quad*4 + r;
            gates[(size_t)grow*512 + col] = f2bfu(acc[t][r] + bc);
        }
    }
}

// ---------------- MFMA recurrent LSTM (8 steps) + projection ----------------
__global__ __launch_bounds__(512) void lstm7(
        const unsigned short* __restrict__ gates, long gn_base, int mbase,
        const unsigned short* __restrict__ whb,
        const float* __restrict__ wcv, const int* __restrict__ flag,
        void* __restrict__ out){
    __shared__ unsigned short hsh[16*136];
    int tid  = threadIdx.x;
    int w    = tid >> 6;
    int lane = tid & 63;
    int quad = lane >> 4, l15 = lane & 15;
    int m0   = mbase + blockIdx.x * 16;
    int isf32 = flag[0];

    bf16x8 bfrag[4][4];
    #pragma unroll
    for (int g=0; g<4; g++)
        #pragma unroll
        for (int kt=0; kt<4; kt++)
            bfrag[g][kt] = *(const bf16x8*)(whb + (size_t)(g*128 + w*16 + l15)*128 + kt*32 + quad*8);

    for (int t=tid; t<16*136; t+=512) hsh[t] = 0;
    f32x4 c = (f32x4){0.f,0.f,0.f,0.f};
    __syncthreads();

    for (int step=0; step<8; step++){
        f32x4 acc[4];
        #pragma unroll
        for (int g=0; g<4; g++){
            #pragma unroll
            for (int r=0; r<4; r++){
                size_t gl = ((size_t)(m0 + quad*4 + r)*8 + step) - gn_base;
                acc[g][r] = bfu2f(gates[gl*512 + g*128 + w*16 + l15]);
            }
        }
        #pragma unroll
        for (int kt=0; kt<4; kt++){
            bf16x8 a = *(const bf16x8*)(hsh + l15*136 + kt*32 + quad*8);
            #pragma unroll
            for (int g=0; g<4; g++)
                acc[g] = __builtin_amdgcn_mfma_f32_16x16x32_bf16(a, bfrag[g][kt], acc[g], 0, 0, 0);
        }
        float hnew[4];
        #pragma unroll
        for (int r=0; r<4; r++){
            float gi = sigmf(acc[0][r]), gf = sigmf(acc[1][r]);
            float gg = tanhfast(acc[2][r]), go = sigmf(acc[3][r]);
            float cc = gf*c[r] + gi*gg;
            c[r] = cc;
            hnew[r] = go*tanhfast(cc);
        }
        __syncthreads();
        #pragma unroll
        for (int r=0; r<4; r++)
            hsh[(quad*4+r)*136 + w*16 + l15] = f2bfu(hnew[r]);
        __syncthreads();
    }
    int r  = tid >> 5;
    int q0 = (tid & 31) * 2;
    float p0 = wcv[OFF_BP + q0], p1 = wcv[OFF_BP + q0 + 1];
    for (int k4=0;k4<32;k4++){
        float4 hv = cvtbf4(*(const ushort4*)(hsh + r*136 + k4*4));
        float4 w0 = *(const float4*)(wcv + OFF_WP + q0*128 + k4*4);
        float4 w1 = *(const float4*)(wcv + OFF_WP + (q0+1)*128 + k4*4);
        p0 += w0.x*hv.x + w0.y*hv.y + w0.z*hv.z + w0.w*hv.w;
        p1 += w1.x*hv.x + w1.y*hv.y + w1.z*hv.z + w1.w*hv.w;
    }
    long o = (long)(m0+r)*64 + q0;
    if (isf32){ ((float*)out)[o] = p0; ((float*)out)[o+1] = p1; }
    else { ((__hip_bfloat16*)out)[o] = __float2bfloat16(p0);
           ((__hip_bfloat16*)out)[o+1] = __float2bfloat16(p1); }
}

extern "C" void kernel_launch(void* const* d_in, const int* in_sizes, int n_in,
                              void* d_out, int out_size, void* d_ws, size_t ws_size,
                              hipStream_t stream){
    const void* x_seq      = d_in[0];
    const int*  edge_index = (const int*)d_in[1];
    const void* edge_weight= d_in[2];

    float* ws    = (float*)d_ws;
    int*   flag  = (int*)(ws + WS_FLAG);
    float* wcv   = ws + WS_WCV;
    unsigned short* whb = (unsigned short*)(ws + WS_WPH);
    unsigned short* wpc = (unsigned short*)(ws + WS_WPC);
    unsigned short* wc0 = (unsigned short*)(ws + WS_WC0);
    float* biasc = ws + WS_BIASC;
    float* deg_o = ws + WS_DEGO;
    float* deg_i = ws + WS_DEGI;
    int*   cnt_i = (int*)(ws + WS_CNTI);
    int*   cnt_o = (int*)(ws + WS_CNTO);
    int*   rp_i  = (int*)(ws + WS_RPI);
    int*   rp_o  = (int*)(ws + WS_RPO);
    int*   cur_i = (int*)(ws + WS_CURI);
    int*   cur_o = (int*)(ws + WS_CURO);
    int2*  csr_i = (int2*)(ws + WS_CSRI);
    int2*  csr_o = (int2*)(ws + WS_CSRO);
    unsigned short* X2 = (unsigned short*)(ws + WS_X2);
    unsigned short* Xb = X2;             // aliases X2 (dead once gather128 writes X2)
    __hip_bfloat16* Hb = (__hip_bfloat16*)(ws + WS_HB);
    unsigned short* GT = (unsigned short*)(ws + WS_GT);
    unsigned short* PQ0 = GT;            // aliases GT (dead before gates written)

    sniff_kernel<<<1, 256, 0, stream>>>((const unsigned int*)edge_weight, flag);
    zero4_kernel<<<(4*GN_+255)/256, 256, 0, stream>>>(ws + WS_DEGO);
    WDesc wd;
    wd.seg[0]  = { d_in[3],  OFF_W0S, 8192  };
    wd.seg[1]  = { d_in[4],  OFF_B0S, 128   };
    wd.seg[2]  = { d_in[5],  OFF_W0D, 8192  };
    wd.seg[3]  = { d_in[6],  OFF_B0D, 128   };
    wd.seg[4]  = { d_in[7],  OFF_W1S, 16384 };
    wd.seg[5]  = { d_in[8],  OFF_B1S, 128   };
    wd.seg[6]  = { d_in[9],  OFF_W1D, 16384 };
    wd.seg[7]  = { d_in[10], OFF_B1D, 128   };
    wd.seg[8]  = { d_in[11], OFF_WIH, 65536 };
    wd.seg[9]  = { d_in[12], OFF_WHH, 65536 };
    wd.seg[10] = { d_in[13], OFF_BIH, 512   };
    wd.seg[11] = { d_in[14], OFF_BHH, 512   };
    wd.seg[12] = { d_in[15], OFF_WP,  8192  };
    wd.seg[13] = { d_in[16], OFF_BP,  64    };
    convert_weights<<<(WCV_TOTAL+255)/256, 256, 0, stream>>>(wd, wcv, flag);
    repack_whh<<<256, 256, 0, stream>>>(wcv, whb);
    repack_wc0<<<64, 256, 0, stream>>>(wcv, wc0);
    compose_wc<<<512, 256, 0, stream>>>(wcv, wpc);
    compose_bias<<<2, 256, 0, stream>>>(wcv, biasc);
    xcvt_kernel<<<(GN_*64+255)/256, 256, 0, stream>>>(x_seq, flag, Xb);

    hist_kernel<<<4000, 256, 0, stream>>>(edge_index, edge_weight, flag, deg_o, deg_i, cnt_i, cnt_o);
    scan_kernel<<<64, 256, 0, stream>>>(cnt_i, cnt_o, rp_i, rp_o, cur_i, cur_o);
    fill_kernel<<<4000, 256, 0, stream>>>(edge_index, edge_weight, flag,
                                          deg_o, deg_i, cur_i, cur_o, csr_i, csr_o);

    // layer 0: gather (bf16 Xb, XCD-swizzled, 8 nodes/wave) -> PQ0 bf16 ; MFMA GEMM -> Hb (bf16)
    gather64<<<2*G_*N_/32, 256, 0, stream>>>(rp_i, rp_o, csr_i, csr_o, Xb, PQ0);
    gemm0<<<2*(GN_/64), 256, 0, stream>>>(PQ0, wc0, wcv, Hb);

    // layer 1: gather (XCD-swizzled, 4 nodes/wave) -> X2 (overwrites Xb); per-half: MFMA gates + MFMA LSTM
    gather128<<<2*G_*N_/16, 256, 0, stream>>>(rp_i, rp_o, csr_i, csr_o,
                                              (const unsigned short*)Hb, X2);

    gemmg<<<8*(HALF_GN/64), 256, 0, stream>>>(X2, wpc, biasc, GT, 0);
    lstm7<<<HALF_M/16, 512, 0, stream>>>(GT, 0L, 0, whb, wcv, flag, d_out);

    gemmg<<<8*(HALF_GN/64), 256, 0, stream>>>(X2, wpc, biasc, GT, HALF_GN);
    lstm7<<<HALF_M/16, 512, 0, stream>>>(GT, (long)HALF_GN, HALF_M, whb, wcv, flag, d_out);
}

// Round 5
// 568.386 us; speedup vs baseline: 1.3292x; 1.3292x over previous
//
#include <hip/hip_runtime.h>
#include <hip/hip_bf16.h>

// Problem constants (B,S,N,F,H,E) = (4,8,4000,64,128,32000)
#define B_  4
#define S_  8
#define N_  4000
#define F_  64
#define H_  128
#define E_  32000
#define G_  (B_*S_)        // 32 graphs
#define GN_ (G_*N_)        // 128000 node rows
#define M_  (B_*N_)        // 16000 LSTM rows
#define GE_ (G_*E_)        // 1,024,000 edges total
#define HALF_GN 64000
#define HALF_M  8000
#define NBLK_   8          // hist/fill blocks per graph
#define EPB_    (E_/NBLK_) // 4000 edges per block

// f32 weight scratch offsets (floats)
#define OFF_W0S 0
#define OFF_B0S 8192
#define OFF_W0D 8320
#define OFF_B0D 16512
#define OFF_W1S 16640
#define OFF_B1S 33024
#define OFF_W1D 33152
#define OFF_B1D 49536
#define OFF_WIH 49664
#define OFF_WHH 115200
#define OFF_BIH 180736
#define OFF_BHH 181248
#define OFF_WP  181760
#define OFF_BP  189952
#define WCV_TOTAL 190016

// workspace layout (float offsets)
#define WS_FLAG   0
#define WS_WCV    16
#define WS_WPH    190032      // Whh bf16 [512][128]: 65536 ushorts
#define WS_WPC    222800      // composed Wc bf16 [512][256]: 131072 ushorts
#define WS_BIASC  288336      // 512 f32
#define WS_DEGO   288848      // deg_o, deg_i, cnt_i, cnt_o contiguous: 4 x 128000 words
#define WS_DEGI   416848
#define WS_CNTI   544848
#define WS_CNTO   672848
#define WS_RPI    800848      // 32*4001
#define WS_RPO    928880
#define WS_CURI   1056912
#define WS_CURO   1184912
#define WS_CSRI   1312912     // int2 x GE
#define WS_CSRO   3360912
#define WS_X2     5408912     // [GN][256] bf16; first 8.2M ushorts alias Xb [GN][64] bf16
#define WS_PART   9608912     // hist partials 4 x [32][8][4000] words = 4,096,000 floats
                              // (lives in X2 tail beyond Xb; dead before gather128 writes X2)
#define WS_HB     21792912    // [GN][128] bf16
#define WS_GT     29984912    // gates half [64000][512] bf16; aliases PQ0 bf16 [GN][128]
#define WS_WC0    46368912    // Wc0 bf16 [128][128]: 16384 ushorts = 8192 floats
// end: 46,377,104 floats = 185.5 MiB (proven budget >= 193 MiB)

typedef __attribute__((ext_vector_type(8))) short bf16x8;
typedef __attribute__((ext_vector_type(4))) float f32x4;
typedef __attribute__((ext_vector_type(8))) unsigned short ushort8;

__device__ inline float bfu2f(unsigned short u){ union{unsigned int i; float f;} v; v.i=((unsigned int)u)<<16; return v.f; }
__device__ inline unsigned short f2bfu(float f){ __hip_bfloat16 b = __float2bfloat16(f); return *(unsigned short*)&b; }
__device__ inline float rcpf(float x){ return __builtin_amdgcn_rcpf(x); }
__device__ inline float sigmf(float x){ return rcpf(1.0f + __expf(-x)); }
__device__ inline float tanhfast(float x){ return 1.0f - 2.0f*rcpf(1.0f + __expf(2.0f*x)); }
__device__ inline float loadf(const void* p, long i, int isf32){
    return isf32 ? ((const float*)p)[i]
                 : __bfloat162float(((const __hip_bfloat16*)p)[i]);
}
__device__ inline float4 cvtbf4(ushort4 u){
    float4 f;
    f.x = __uint_as_float(((unsigned)u.x)<<16);
    f.y = __uint_as_float(((unsigned)u.y)<<16);
    f.z = __uint_as_float(((unsigned)u.z)<<16);
    f.w = __uint_as_float(((unsigned)u.w)<<16);
    return f;
}

// ---------------- dtype sniff (inputs f32 vs bf16) ----------------
__global__ void sniff_kernel(const unsigned int* __restrict__ ew, int* __restrict__ flag){
    __shared__ int s;
    if (threadIdx.x == 0) s = 0;
    __syncthreads();
    unsigned int lo = ew[threadIdx.x] & 0xFFFFu;
    if (lo > 0x3F80u) atomicOr(&s, 1);
    __syncthreads();
    if (threadIdx.x == 0) flag[0] = s;   // 1 => inputs are f32
}

// ---------------- weight conversion to f32 scratch ----------------
struct WSeg { const void* src; int base; int n; };
struct WDesc { WSeg seg[14]; };
__global__ void convert_weights(WDesc d, float* __restrict__ dst, const int* __restrict__ flag){
    int isf32 = flag[0];
    int idx = blockIdx.x*256 + threadIdx.x;
    #pragma unroll
    for (int s=0;s<14;s++){
        int off = idx - d.seg[s].base;
        if (off >= 0 && off < d.seg[s].n){
            dst[idx] = loadf(d.seg[s].src, off, isf32);
            return;
        }
    }
}

// ---------------- Whh bf16 copy ----------------
__global__ void repack_whh(const float* __restrict__ wcv, unsigned short* __restrict__ whb){
    int idx = blockIdx.x*256 + threadIdx.x;   // < 65536
    whb[idx] = f2bfu(wcv[OFF_WHH + idx]);
}

// ---------------- layer-0 composed weights: Wc0[n][k] bf16 [128][128] ----------------
// k<64: 0.5*W0s[n][k] ; k>=64: 0.5*W0d[n][k-64]
__global__ void repack_wc0(const float* __restrict__ wcv, unsigned short* __restrict__ wc0){
    int idx = blockIdx.x*256 + threadIdx.x;   // < 16384
    int k = idx & 127, n = idx >> 7;
    float v = (k < 64) ? 0.5f*wcv[OFF_W0S + n*64 + k] : 0.5f*wcv[OFF_W0D + n*64 + (k-64)];
    wc0[idx] = f2bfu(v);
}

// ---------------- x_seq -> bf16 Xb [GN][64] ----------------
__global__ void xcvt_kernel(const void* __restrict__ x, const int* __restrict__ flag,
                            unsigned short* __restrict__ Xb){
    long idx = (long)blockIdx.x*256 + threadIdx.x;
    if (idx >= (long)GN_*64) return;
    Xb[idx] = f2bfu(loadf(x, idx, flag[0]));
}

// ---------------- composed weights: Wc[n][k] bf16 [512][256] ----------------
__global__ __launch_bounds__(256) void compose_wc(const float* __restrict__ wcv,
                                                  unsigned short* __restrict__ wpc){
    int n = blockIdx.x;        // 512 blocks
    int k = threadIdx.x;       // 256
    const float* wih = wcv + OFF_WIH + n*128;
    const float* w1  = (k < 128) ? (wcv + OFF_W1S + k) : (wcv + OFF_W1D + (k-128));
    float s = 0.f;
    for (int h=0; h<128; h++) s += wih[h] * w1[h*128];
    wpc[n*256 + k] = f2bfu(0.5f * s);
}

// biasc[n] = bih[n]+bhh[n] + sum_h Wih[n][h]*0.5*(b1s[h]+b1d[h])
__global__ void compose_bias(const float* __restrict__ wcv, float* __restrict__ biasc){
    int n = blockIdx.x*256 + threadIdx.x;
    if (n >= 512) return;
    float s = wcv[OFF_BIH+n] + wcv[OFF_BHH+n];
    const float* wih = wcv + OFF_WIH + n*128;
    for (int h=0; h<128; h++) s += wih[h] * 0.5f*(wcv[OFF_B1S+h] + wcv[OFF_B1D+h]);
    biasc[n] = s;
}

// ---------------- histogram: per-(graph, edge-block) LDS partials ----------------
// R5: no global atomics (device-scope atomics bypass L2 -> per-op fabric writes, the
// R4 regression). 8 blocks/graph x 4000 edges, LDS histogram, plain-store partials.
// Partials P[arr][g][b][n], arr: 0=deg_o 1=deg_i 2=cnt_i 3=cnt_o.
__global__ __launch_bounds__(1024) void hist_kernel(
        const int* __restrict__ ei, const void* __restrict__ ew, const int* __restrict__ flag,
        float* __restrict__ part){
    __shared__ float wdo[N_], wdi[N_];
    __shared__ int   co[N_],  ci[N_];
    int xcd  = blockIdx.x & 7;
    int r2   = blockIdx.x >> 3;
    int g    = xcd*4 + (r2 & 3);
    int b    = r2 >> 2;                     // 0..7
    int tid  = threadIdx.x;
    int isf32 = flag[0];
    for (int i=tid;i<N_;i+=1024){ wdo[i]=0.f; wdi[i]=0.f; co[i]=0; ci[i]=0; }
    __syncthreads();
    const int* eib = ei + g*2*E_;
    int e0 = b*EPB_;
    for (int e=e0+tid; e<e0+EPB_; e+=1024){
        int s = eib[e], d = eib[E_+e];
        float w = loadf(ew, (long)g*E_+e, isf32);
        atomicAdd(&wdo[s], w); atomicAdd(&wdi[d], w);
        atomicAdd(&co[s], 1);  atomicAdd(&ci[d], 1);
    }
    __syncthreads();
    float* Pdo = part + (size_t)(0*G_ + g)*NBLK_*N_ + (size_t)b*N_;
    float* Pdi = part + (size_t)(1*G_ + g)*NBLK_*N_ + (size_t)b*N_;
    int*   Pci = (int*)part + (size_t)(2*G_ + g)*NBLK_*N_ + (size_t)b*N_;
    int*   Pco = (int*)part + (size_t)(3*G_ + g)*NBLK_*N_ + (size_t)b*N_;
    for (int i=tid;i<N_;i+=1024){
        Pdo[i] = wdo[i]; Pdi[i] = wdi[i];
        Pci[i] = ci[i];  Pco[i] = co[i];
    }
}

// ---------------- reduce partials -> deg/cnt; counts -> per-block exclusive prefix ----------------
__global__ __launch_bounds__(256) void reduce_hist(
        float* __restrict__ part,
        float* __restrict__ deg_o, float* __restrict__ deg_i,
        int* __restrict__ cnt_in, int* __restrict__ cnt_out){
    int g = blockIdx.x >> 4;
    int n = (blockIdx.x & 15)*256 + threadIdx.x;
    if (n >= N_) return;
    float* Pdo = part + (size_t)(0*G_ + g)*NBLK_*N_;
    float* Pdi = part + (size_t)(1*G_ + g)*NBLK_*N_;
    int*   Pci = (int*)part + (size_t)(2*G_ + g)*NBLK_*N_;
    int*   Pco = (int*)part + (size_t)(3*G_ + g)*NBLK_*N_;
    float sdo = 0.f, sdi = 0.f;
    int sci = 0, sco = 0;
    #pragma unroll
    for (int b=0;b<NBLK_;b++){
        size_t idx = (size_t)b*N_ + n;
        sdo += Pdo[idx]; sdi += Pdi[idx];
        int vi = Pci[idx], vo = Pco[idx];
        Pci[idx] = sci;  Pco[idx] = sco;   // exclusive prefix for fill
        sci += vi; sco += vo;
    }
    deg_o[g*N_+n] = sdo; deg_i[g*N_+n] = sdi;
    cnt_in[g*N_+n] = sci; cnt_out[g*N_+n] = sco;
}

// ---------------- exclusive scan -> row_ptr ----------------
__global__ __launch_bounds__(256) void scan_kernel(
        const int* __restrict__ cnt_in, const int* __restrict__ cnt_out,
        int* __restrict__ rp_in, int* __restrict__ rp_out){
    __shared__ int part[256], pref[256];
    int g = blockIdx.x & 31, dir = blockIdx.x >> 5;
    const int* cnt = (dir ? cnt_out : cnt_in) + g*N_;
    int* rp  = (dir ? rp_out  : rp_in)  + g*(N_+1);
    int tid = threadIdx.x, base = tid*16;
    int sum = 0;
    for (int i=0;i<16;i++){ int p = base+i; if (p < N_) sum += cnt[p]; }
    part[tid] = sum;
    __syncthreads();
    if (tid == 0){ int run = 0; for (int j=0;j<256;j++){ pref[j] = run; run += part[j]; } }
    __syncthreads();
    int run = pref[tid];
    for (int i=0;i<16;i++){
        int p = base+i;
        if (p < N_){ rp[p] = run; run += cnt[p]; }
    }
    if (tid == 255) rp[N_] = run;
}

// ---------------- fill CSR (no global atomics) ----------------
// Same (g,b) edge partition as hist. slot = rp[n] + cum[g][b][n] + LDS-local index.
__global__ __launch_bounds__(1024) void fill_kernel(
        const int* __restrict__ ei, const void* __restrict__ ew,
        const int* __restrict__ flag,
        const float* __restrict__ deg_o, const float* __restrict__ deg_i,
        const int* __restrict__ rp_in, const int* __restrict__ rp_out,
        const float* __restrict__ part,
        int2* __restrict__ csr_in, int2* __restrict__ csr_out){
    __shared__ int lci[N_], lco[N_];
    int xcd  = blockIdx.x & 7;
    int r2   = blockIdx.x >> 3;
    int g    = xcd*4 + (r2 & 3);
    int b    = r2 >> 2;
    int tid  = threadIdx.x;
    int isf32 = flag[0];
    for (int i=tid;i<N_;i+=1024){ lci[i]=0; lco[i]=0; }
    __syncthreads();
    const int* eib = ei + g*2*E_;
    const int* cumI = (const int*)part + (size_t)(2*G_ + g)*NBLK_*N_ + (size_t)b*N_;
    const int* cumO = (const int*)part + (size_t)(3*G_ + g)*NBLK_*N_ + (size_t)b*N_;
    const int* rpi = rp_in  + g*(N_+1);
    const int* rpo = rp_out + g*(N_+1);
    int2* ci = csr_in  + (long)g*E_;
    int2* co = csr_out + (long)g*E_;
    int e0 = b*EPB_;
    for (int e=e0+tid; e<e0+EPB_; e+=1024){
        int s = eib[e], d = eib[E_+e];
        float dout = deg_o[g*N_+s], din = deg_i[g*N_+d];
        float io = dout > 0.f ? rsqrtf(fmaxf(dout, 1e-12f)) : 0.f;
        float ii = din  > 0.f ? rsqrtf(fmaxf(din , 1e-12f)) : 0.f;
        float nrm = loadf(ew, (long)g*E_ + e, isf32) * io * ii;
        int li = atomicAdd(&lci[d], 1);
        ci[rpi[d] + cumI[d] + li] = make_int2(s, __float_as_int(nrm));
        int lo = atomicAdd(&lco[s], 1);
        co[rpo[s] + cumO[s] + lo] = make_int2(d, __float_as_int(nrm));
    }
}

// ---------------- gather layer 0 -> PQ0 bf16 [GN][128] (dir0 cols 0..63, dir1 64..127) ----------------
// R2: 8 nodes per wave, ushort8 (16B) per lane, 8 lanes cover a 64-col row.
__global__ __launch_bounds__(256) void gather64(
        const int* __restrict__ rp_in, const int* __restrict__ rp_out,
        const int2* __restrict__ csr_in, const int2* __restrict__ csr_out,
        const unsigned short* __restrict__ Xb,
        unsigned short* __restrict__ PQ0){
    int xcd  = blockIdx.x & 7;
    int rest = blockIdx.x >> 3;            // 0..999
    int g    = xcd*4 + (rest & 3);         // wave-uniform
    int chunk= rest >> 2;                  // 0..249
    int wave = threadIdx.x >> 6;
    int lane = threadIdx.x & 63;
    int sub  = lane >> 3;                  // node slot 0..7
    int li   = lane & 7;                   // col group (8 bf16 each)
    int wl   = chunk*32 + wave*8 + sub;    // 0..7999
    int dir  = wl >= N_;  int n = wl - dir*N_;
    const int*  rp  = (dir ? rp_out : rp_in) + g*(N_+1);
    const int2* csr = (dir ? csr_out : csr_in) + (long)g*E_;
    int pb = rp[n], pe = rp[n+1];
    int plast = max(pe - 1, 0);
    const unsigned short* base = Xb + (size_t)g*N_*64;   // scalar base
    float acc[8];
    #pragma unroll
    for (int j=0;j<8;j++) acc[j] = 0.f;
    for (int p = pb; __any(p < pe); p += 4){
        float w[4]; ushort8 v[4];
        #pragma unroll
        for (int i=0;i<4;i++){
            int pi = p+i;
            int2 ent = csr[min(pi, plast)];
            w[i] = (pi < pe) ? __int_as_float(ent.y) : 0.f;
            v[i] = *(const ushort8*)(base + ent.x*64 + li*8);
        }
        #pragma unroll
        for (int i=0;i<4;i++)
            #pragma unroll
            for (int j=0;j<8;j++)
                acc[j] += w[i]*bfu2f(v[i][j]);
    }
    ushort8 o;
    #pragma unroll
    for (int j=0;j<8;j++) o[j] = f2bfu(acc[j]);
    *(ushort8*)(PQ0 + (size_t)(g*N_+n)*128 + dir*64 + li*8) = o;
}

// ---------------- gather layer 1 -> X2 bf16 [GN][256] (XCD-swizzled) ----------------
// R2: 4 nodes per wave, ushort8 per lane, 16 lanes cover a 128-col row.
__global__ __launch_bounds__(256) void gather128(
        const int* __restrict__ rp_in, const int* __restrict__ rp_out,
        const int2* __restrict__ csr_in, const int2* __restrict__ csr_out,
        const unsigned short* __restrict__ hb,
        unsigned short* __restrict__ X2){
    int xcd  = blockIdx.x & 7;
    int rest = blockIdx.x >> 3;            // 0..1999
    int g    = xcd*4 + (rest & 3);         // wave-uniform
    int chunk= rest >> 2;                  // 0..499
    int wave = threadIdx.x >> 6;
    int lane = threadIdx.x & 63;
    int sub  = lane >> 4;                  // node slot 0..3
    int li   = lane & 15;                  // col group (8 bf16 each)
    int wl   = chunk*16 + wave*4 + sub;    // 0..7999
    int dir  = wl >= N_;  int n = wl - dir*N_;
    const int*  rp  = (dir ? rp_out : rp_in) + g*(N_+1);
    const int2* csr = (dir ? csr_out : csr_in) + (long)g*E_;
    int pb = rp[n], pe = rp[n+1];
    int plast = max(pe - 1, 0);
    const unsigned short* base = hb + (size_t)g*N_*128;  // scalar base
    float acc[8];
    #pragma unroll
    for (int j=0;j<8;j++) acc[j] = 0.f;
    for (int p = pb; __any(p < pe); p += 4){
        float w[4]; ushort8 v[4];
        #pragma unroll
        for (int i=0;i<4;i++){
            int pi = p+i;
            int2 ent = csr[min(pi, plast)];
            w[i] = (pi < pe) ? __int_as_float(ent.y) : 0.f;
            v[i] = *(const ushort8*)(base + ent.x*128 + li*8);
        }
        #pragma unroll
        for (int i=0;i<4;i++)
            #pragma unroll
            for (int j=0;j<8;j++)
                acc[j] += w[i]*bfu2f(v[i][j]);
    }
    ushort8 o;
    #pragma unroll
    for (int j=0;j<8;j++) o[j] = f2bfu(acc[j]);
    *(ushort8*)(X2 + (size_t)(g*N_+n)*256 + dir*128 + li*8) = o;
}

// ---------------- MFMA layer-0 GEMM: Hb[GN][128] = PQ0 @ Wc0^T + 0.5(b0s+b0d) ----------------
__global__ __launch_bounds__(256) void gemm0(
        const unsigned short* __restrict__ PQ0, const unsigned short* __restrict__ wc0,
        const float* __restrict__ wcv, __hip_bfloat16* __restrict__ Hb){
    __shared__ unsigned short As[2][64*40];
    int tid  = threadIdx.x;
    int wave = tid >> 6, lane = tid & 63;
    int quad = lane >> 4, l16 = lane & 15;
    int nb = blockIdx.x & 1, mb = blockIdx.x >> 1;
    int m0 = mb*64;
    int col = nb*64 + wave*16 + l16;
    bf16x8 bq[4];
    #pragma unroll
    for (int ks=0; ks<4; ks++)
        bq[ks] = *(const bf16x8*)(wc0 + (size_t)col*128 + ks*32 + quad*8);
    f32x4 acc[4];
    #pragma unroll
    for (int t=0;t<4;t++) acc[t] = (f32x4){0.f,0.f,0.f,0.f};
    int srow = tid>>2, sch = tid&3;
    const unsigned short* src_base = PQ0 + (size_t)(m0 + srow)*128 + sch*8;
    *(float4*)(&As[0][srow*40 + sch*8]) = *(const float4*)(src_base);
    __syncthreads();
    for (int ks=0; ks<4; ks++){
        if (ks < 3)
            *(float4*)(&As[(ks+1)&1][srow*40 + sch*8]) = *(const float4*)(src_base + (ks+1)*32);
        const unsigned short* ab = As[ks&1];
        #pragma unroll
        for (int t=0;t<4;t++){
            bf16x8 a = *(const bf16x8*)(ab + (t*16 + l16)*40 + quad*8);
            acc[t] = __builtin_amdgcn_mfma_f32_16x16x32_bf16(a, bq[ks], acc[t], 0, 0, 0);
        }
        __syncthreads();
    }
    float bias = 0.5f*(wcv[OFF_B0S+col] + wcv[OFF_B0D+col]);
    #pragma unroll
    for (int t=0;t<4;t++){
        #pragma unroll
        for (int r=0;r<4;r++){
            int grow = m0 + t*16 + quad*4 + r;
            Hb[(size_t)grow*128 + col] = __float2bfloat16(acc[t][r] + bias);
        }
    }
}

// ---------------- MFMA gates GEMM: gates[64000][512] = X2 @ Wc^T + biasc ----------------
__global__ __launch_bounds__(256) void gemmg(
        const unsigned short* __restrict__ X2, const unsigned short* __restrict__ wpc,
        const float* __restrict__ biasc, unsigned short* __restrict__ gates, int gn_base){
    __shared__ unsigned short As[2][64*40];
    int tid  = threadIdx.x;
    int wave = tid >> 6, lane = tid & 63;
    int quad = lane >> 4, l16 = lane & 15;
    int nb = blockIdx.x & 7, mb = blockIdx.x >> 3;
    int m0 = mb*64;
    int col = nb*64 + wave*16 + l16;
    bf16x8 bq[8];
    #pragma unroll
    for (int ks=0; ks<8; ks++)
        bq[ks] = *(const bf16x8*)(wpc + (size_t)col*256 + ks*32 + quad*8);
    f32x4 acc[4];
    #pragma unroll
    for (int t=0;t<4;t++) acc[t] = (f32x4){0.f,0.f,0.f,0.f};
    int srow = tid>>2, sch = tid&3;
    const unsigned short* src_base = X2 + (size_t)(gn_base + m0 + srow)*256 + sch*8;
    *(float4*)(&As[0][srow*40 + sch*8]) = *(const float4*)(src_base);
    __syncthreads();
    for (int ks=0; ks<8; ks++){
        if (ks < 7)
            *(float4*)(&As[(ks+1)&1][srow*40 + sch*8]) = *(const float4*)(src_base + (ks+1)*32);
        const unsigned short* ab = As[ks&1];
        #pragma unroll
        for (int t=0;t<4;t++){
            bf16x8 a = *(const bf16x8*)(ab + (t*16 + l16)*40 + quad*8);
            acc[t] = __builtin_amdgcn_mfma_f32_16x16x32_bf16(a, bq[ks], acc[t], 0, 0, 0);
        }
        __syncthreads();
    }
    float bc = biasc[col];
    #pragma unroll
    for (int t=0;t<4;t++){
        #pragma unroll
        for (int r=0;r<4;r++){
            int grow = m0 + t*16 + quad*4 + r;
            gates[(size_t)grow*512 + col] = f2bfu(acc[t][r] + bc);
        }
    }
}

// ---------------- MFMA recurrent LSTM (8 steps) + projection ----------------
__global__ __launch_bounds__(512) void lstm7(
        const unsigned short* __restrict__ gates, long gn_base, int mbase,
        const unsigned short* __restrict__ whb,
        const float* __restrict__ wcv, const int* __restrict__ flag,
        void* __restrict__ out){
    __shared__ unsigned short hsh[16*136];
    int tid  = threadIdx.x;
    int w    = tid >> 6;
    int lane = tid & 63;
    int quad = lane >> 4, l15 = lane & 15;
    int m0   = mbase + blockIdx.x * 16;
    int isf32 = flag[0];

    bf16x8 bfrag[4][4];
    #pragma unroll
    for (int g=0; g<4; g++)
        #pragma unroll
        for (int kt=0; kt<4; kt++)
            bfrag[g][kt] = *(const bf16x8*)(whb + (size_t)(g*128 + w*16 + l15)*128 + kt*32 + quad*8);

    for (int t=tid; t<16*136; t+=512) hsh[t] = 0;
    f32x4 c = (f32x4){0.f,0.f,0.f,0.f};
    __syncthreads();

    for (int step=0; step<8; step++){
        f32x4 acc[4];
        #pragma unroll
        for (int g=0; g<4; g++){
            #pragma unroll
            for (int r=0; r<4; r++){
                size_t gl = ((size_t)(m0 + quad*4 + r)*8 + step) - gn_base;
                acc[g][r] = bfu2f(gates[gl*512 + g*128 + w*16 + l15]);
            }
        }
        #pragma unroll
        for (int kt=0; kt<4; kt++){
            bf16x8 a = *(const bf16x8*)(hsh + l15*136 + kt*32 + quad*8);
            #pragma unroll
            for (int g=0; g<4; g++)
                acc[g] = __builtin_amdgcn_mfma_f32_16x16x32_bf16(a, bfrag[g][kt], acc[g], 0, 0, 0);
        }
        float hnew[4];
        #pragma unroll
        for (int r=0; r<4; r++){
            float gi = sigmf(acc[0][r]), gf = sigmf(acc[1][r]);
            float gg = tanhfast(acc[2][r]), go = sigmf(acc[3][r]);
            float cc = gf*c[r] + gi*gg;
            c[r] = cc;
            hnew[r] = go*tanhfast(cc);
        }
        __syncthreads();
        #pragma unroll
        for (int r=0; r<4; r++)
            hsh[(quad*4+r)*136 + w*16 + l15] = f2bfu(hnew[r]);
        __syncthreads();
    }
    int r  = tid >> 5;
    int q0 = (tid & 31) * 2;
    float p0 = wcv[OFF_BP + q0], p1 = wcv[OFF_BP + q0 + 1];
    for (int k4=0;k4<32;k4++){
        float4 hv = cvtbf4(*(const ushort4*)(hsh + r*136 + k4*4));
        float4 w0 = *(const float4*)(wcv + OFF_WP + q0*128 + k4*4);
        float4 w1 = *(const float4*)(wcv + OFF_WP + (q0+1)*128 + k4*4);
        p0 += w0.x*hv.x + w0.y*hv.y + w0.z*hv.z + w0.w*hv.w;
        p1 += w1.x*hv.x + w1.y*hv.y + w1.z*hv.z + w1.w*hv.w;
    }
    long o = (long)(m0+r)*64 + q0;
    if (isf32){ ((float*)out)[o] = p0; ((float*)out)[o+1] = p1; }
    else { ((__hip_bfloat16*)out)[o] = __float2bfloat16(p0);
           ((__hip_bfloat16*)out)[o+1] = __float2bfloat16(p1); }
}

extern "C" void kernel_launch(void* const* d_in, const int* in_sizes, int n_in,
                              void* d_out, int out_size, void* d_ws, size_t ws_size,
                              hipStream_t stream){
    const void* x_seq      = d_in[0];
    const int*  edge_index = (const int*)d_in[1];
    const void* edge_weight= d_in[2];

    float* ws    = (float*)d_ws;
    int*   flag  = (int*)(ws + WS_FLAG);
    float* wcv   = ws + WS_WCV;
    unsigned short* whb = (unsigned short*)(ws + WS_WPH);
    unsigned short* wpc = (unsigned short*)(ws + WS_WPC);
    unsigned short* wc0 = (unsigned short*)(ws + WS_WC0);
    float* biasc = ws + WS_BIASC;
    float* deg_o = ws + WS_DEGO;
    float* deg_i = ws + WS_DEGI;
    int*   cnt_i = (int*)(ws + WS_CNTI);
    int*   cnt_o = (int*)(ws + WS_CNTO);
    int*   rp_i  = (int*)(ws + WS_RPI);
    int*   rp_o  = (int*)(ws + WS_RPO);
    float* partb = ws + WS_PART;
    int2*  csr_i = (int2*)(ws + WS_CSRI);
    int2*  csr_o = (int2*)(ws + WS_CSRO);
    unsigned short* X2 = (unsigned short*)(ws + WS_X2);
    unsigned short* Xb = X2;             // aliases X2 (dead once gather128 writes X2)
    __hip_bfloat16* Hb = (__hip_bfloat16*)(ws + WS_HB);
    unsigned short* GT = (unsigned short*)(ws + WS_GT);
    unsigned short* PQ0 = GT;            // aliases GT (dead before gates written)

    sniff_kernel<<<1, 256, 0, stream>>>((const unsigned int*)edge_weight, flag);
    WDesc wd;
    wd.seg[0]  = { d_in[3],  OFF_W0S, 8192  };
    wd.seg[1]  = { d_in[4],  OFF_B0S, 128   };
    wd.seg[2]  = { d_in[5],  OFF_W0D, 8192  };
    wd.seg[3]  = { d_in[6],  OFF_B0D, 128   };
    wd.seg[4]  = { d_in[7],  OFF_W1S, 16384 };
    wd.seg[5]  = { d_in[8],  OFF_B1S, 128   };
    wd.seg[6]  = { d_in[9],  OFF_W1D, 16384 };
    wd.seg[7]  = { d_in[10], OFF_B1D, 128   };
    wd.seg[8]  = { d_in[11], OFF_WIH, 65536 };
    wd.seg[9]  = { d_in[12], OFF_WHH, 65536 };
    wd.seg[10] = { d_in[13], OFF_BIH, 512   };
    wd.seg[11] = { d_in[14], OFF_BHH, 512   };
    wd.seg[12] = { d_in[15], OFF_WP,  8192  };
    wd.seg[13] = { d_in[16], OFF_BP,  64    };
    convert_weights<<<(WCV_TOTAL+255)/256, 256, 0, stream>>>(wd, wcv, flag);
    repack_whh<<<256, 256, 0, stream>>>(wcv, whb);
    repack_wc0<<<64, 256, 0, stream>>>(wcv, wc0);
    compose_wc<<<512, 256, 0, stream>>>(wcv, wpc);
    compose_bias<<<2, 256, 0, stream>>>(wcv, biasc);
    xcvt_kernel<<<(GN_*64+255)/256, 256, 0, stream>>>(x_seq, flag, Xb);

    hist_kernel<<<G_*NBLK_, 1024, 0, stream>>>(edge_index, edge_weight, flag, partb);
    reduce_hist<<<G_*16, 256, 0, stream>>>(partb, deg_o, deg_i, cnt_i, cnt_o);
    scan_kernel<<<64, 256, 0, stream>>>(cnt_i, cnt_o, rp_i, rp_o);
    fill_kernel<<<G_*NBLK_, 1024, 0, stream>>>(edge_index, edge_weight, flag,
                                               deg_o, deg_i, rp_i, rp_o, partb, csr_i, csr_o);

    // layer 0: gather (bf16 Xb, XCD-swizzled, 8 nodes/wave) -> PQ0 bf16 ; MFMA GEMM -> Hb (bf16)
    gather64<<<2*G_*N_/32, 256, 0, stream>>>(rp_i, rp_o, csr_i, csr_o, Xb, PQ0);
    gemm0<<<2*(GN_/64), 256, 0, stream>>>(PQ0, wc0, wcv, Hb);

    // layer 1: gather (XCD-swizzled, 4 nodes/wave) -> X2 (overwrites Xb); per-half: MFMA gates + MFMA LSTM
    gather128<<<2*G_*N_/16, 256, 0, stream>>>(rp_i, rp_o, csr_i, csr_o,
                                              (const unsigned short*)Hb, X2);

    gemmg<<<8*(HALF_GN/64), 256, 0, stream>>>(X2, wpc, biasc, GT, 0);
    lstm7<<<HALF_M/16, 512, 0, stream>>>(GT, 0L, 0, whb, wcv, flag, d_out);

    gemmg<<<8*(HALF_GN/64), 256, 0, stream>>>(X2, wpc, biasc, GT, HALF_GN);
    lstm7<<<HALF_M/16, 512, 0, stream>>>(GT, (long)HALF_GN, HALF_M, whb, wcv, flag, d_out);
}

// Round 6
// 550.642 us; speedup vs baseline: 1.3720x; 1.0322x over previous
//
#include <hip/hip_runtime.h>
#include <hip/hip_bf16.h>

// Problem constants (B,S,N,F,H,E) = (4,8,4000,64,128,32000)
#define B_  4
#define S_  8
#define N_  4000
#define F_  64
#define H_  128
#define E_  32000
#define G_  (B_*S_)        // 32 graphs
#define GN_ (G_*N_)        // 128000 node rows
#define M_  (B_*N_)        // 16000 LSTM rows
#define GE_ (G_*E_)        // 1,024,000 edges total
#define HALF_GN 64000
#define HALF_M  8000
#define NBLK_   8          // hist/fill blocks per graph
#define EPB_    (E_/NBLK_) // 4000 edges per block

// f32 weight scratch offsets (floats)
#define OFF_W0S 0
#define OFF_B0S 8192
#define OFF_W0D 8320
#define OFF_B0D 16512
#define OFF_W1S 16640
#define OFF_B1S 33024
#define OFF_W1D 33152
#define OFF_B1D 49536
#define OFF_WIH 49664
#define OFF_WHH 115200
#define OFF_BIH 180736
#define OFF_BHH 181248
#define OFF_WP  181760
#define OFF_BP  189952
#define WCV_TOTAL 190016

// workspace layout (float offsets)
#define WS_FLAG   0
#define WS_WCV    16
#define WS_WPH    190032      // Whh bf16 [512][128]: 65536 ushorts
#define WS_WPC    222800      // composed Wc bf16 [512][256]: 131072 ushorts
#define WS_BIASC  288336      // 512 f32
#define WS_DEGO   288848      // deg_o, deg_i, cnt_i, cnt_o contiguous: 4 x 128000 words
#define WS_DEGI   416848
#define WS_CNTI   544848
#define WS_CNTO   672848
#define WS_RPI    800848      // 32*4001
#define WS_RPO    928880
#define WS_CURI   1056912
#define WS_CURO   1184912
#define WS_CSRI   1312912     // int2 x GE
#define WS_CSRO   3360912
#define WS_X2     5408912     // [GN][256] bf16; first 8.2M ushorts alias Xb [GN][64] bf16
#define WS_PART   9608912     // hist partials 4 x [32][8][4000] words = 4,096,000 floats
#define WS_HB     21792912    // [GN][128] bf16
#define WS_GT     29984912    // gates3 half [8000][512][8] bf16; aliases PQ0 bf16 [GN][128]
#define WS_WC0    46368912    // Wc0 bf16 [128][128]: 16384 ushorts = 8192 floats
// end: 46,377,104 floats = 185.5 MiB (proven budget >= 193 MiB)

typedef __attribute__((ext_vector_type(8))) short bf16x8;
typedef __attribute__((ext_vector_type(4))) float f32x4;
typedef __attribute__((ext_vector_type(8))) unsigned short ushort8;

__device__ inline float bfu2f(unsigned short u){ union{unsigned int i; float f;} v; v.i=((unsigned int)u)<<16; return v.f; }
__device__ inline unsigned short f2bfu(float f){ __hip_bfloat16 b = __float2bfloat16(f); return *(unsigned short*)&b; }
__device__ inline float rcpf(float x){ return __builtin_amdgcn_rcpf(x); }
__device__ inline float sigmf(float x){ return rcpf(1.0f + __expf(-x)); }
__device__ inline float tanhfast(float x){ return 1.0f - 2.0f*rcpf(1.0f + __expf(2.0f*x)); }
__device__ inline float loadf(const void* p, long i, int isf32){
    return isf32 ? ((const float*)p)[i]
                 : __bfloat162float(((const __hip_bfloat16*)p)[i]);
}
__device__ inline float4 cvtbf4(ushort4 u){
    float4 f;
    f.x = __uint_as_float(((unsigned)u.x)<<16);
    f.y = __uint_as_float(((unsigned)u.y)<<16);
    f.z = __uint_as_float(((unsigned)u.z)<<16);
    f.w = __uint_as_float(((unsigned)u.w)<<16);
    return f;
}

// ---------------- dtype sniff (inputs f32 vs bf16) ----------------
__global__ void sniff_kernel(const unsigned int* __restrict__ ew, int* __restrict__ flag){
    __shared__ int s;
    if (threadIdx.x == 0) s = 0;
    __syncthreads();
    unsigned int lo = ew[threadIdx.x] & 0xFFFFu;
    if (lo > 0x3F80u) atomicOr(&s, 1);
    __syncthreads();
    if (threadIdx.x == 0) flag[0] = s;   // 1 => inputs are f32
}

// ---------------- weight conversion to f32 scratch ----------------
struct WSeg { const void* src; int base; int n; };
struct WDesc { WSeg seg[14]; };
__global__ void convert_weights(WDesc d, float* __restrict__ dst, const int* __restrict__ flag){
    int isf32 = flag[0];
    int idx = blockIdx.x*256 + threadIdx.x;
    #pragma unroll
    for (int s=0;s<14;s++){
        int off = idx - d.seg[s].base;
        if (off >= 0 && off < d.seg[s].n){
            dst[idx] = loadf(d.seg[s].src, off, isf32);
            return;
        }
    }
}

// ---------------- Whh bf16 copy ----------------
__global__ void repack_whh(const float* __restrict__ wcv, unsigned short* __restrict__ whb){
    int idx = blockIdx.x*256 + threadIdx.x;   // < 65536
    whb[idx] = f2bfu(wcv[OFF_WHH + idx]);
}

// ---------------- layer-0 composed weights: Wc0[n][k] bf16 [128][128] ----------------
__global__ void repack_wc0(const float* __restrict__ wcv, unsigned short* __restrict__ wc0){
    int idx = blockIdx.x*256 + threadIdx.x;   // < 16384
    int k = idx & 127, n = idx >> 7;
    float v = (k < 64) ? 0.5f*wcv[OFF_W0S + n*64 + k] : 0.5f*wcv[OFF_W0D + n*64 + (k-64)];
    wc0[idx] = f2bfu(v);
}

// ---------------- x_seq -> bf16 Xb [GN][64] ----------------
__global__ void xcvt_kernel(const void* __restrict__ x, const int* __restrict__ flag,
                            unsigned short* __restrict__ Xb){
    long idx = (long)blockIdx.x*256 + threadIdx.x;
    if (idx >= (long)GN_*64) return;
    Xb[idx] = f2bfu(loadf(x, idx, flag[0]));
}

// ---------------- composed weights: Wc[n][k] bf16 [512][256] ----------------
__global__ __launch_bounds__(256) void compose_wc(const float* __restrict__ wcv,
                                                  unsigned short* __restrict__ wpc){
    int n = blockIdx.x;        // 512 blocks
    int k = threadIdx.x;       // 256
    const float* wih = wcv + OFF_WIH + n*128;
    const float* w1  = (k < 128) ? (wcv + OFF_W1S + k) : (wcv + OFF_W1D + (k-128));
    float s = 0.f;
    for (int h=0; h<128; h++) s += wih[h] * w1[h*128];
    wpc[n*256 + k] = f2bfu(0.5f * s);
}

// biasc[n] = bih[n]+bhh[n] + sum_h Wih[n][h]*0.5*(b1s[h]+b1d[h])
__global__ void compose_bias(const float* __restrict__ wcv, float* __restrict__ biasc){
    int n = blockIdx.x*256 + threadIdx.x;
    if (n >= 512) return;
    float s = wcv[OFF_BIH+n] + wcv[OFF_BHH+n];
    const float* wih = wcv + OFF_WIH + n*128;
    for (int h=0; h<128; h++) s += wih[h] * 0.5f*(wcv[OFF_B1S+h] + wcv[OFF_B1D+h]);
    biasc[n] = s;
}

// ---------------- histogram: per-(graph, edge-block) LDS partials ----------------
__global__ __launch_bounds__(1024) void hist_kernel(
        const int* __restrict__ ei, const void* __restrict__ ew, const int* __restrict__ flag,
        float* __restrict__ part){
    __shared__ float wdo[N_], wdi[N_];
    __shared__ int   co[N_],  ci[N_];
    int xcd  = blockIdx.x & 7;
    int r2   = blockIdx.x >> 3;
    int g    = xcd*4 + (r2 & 3);
    int b    = r2 >> 2;                     // 0..7
    int tid  = threadIdx.x;
    int isf32 = flag[0];
    for (int i=tid;i<N_;i+=1024){ wdo[i]=0.f; wdi[i]=0.f; co[i]=0; ci[i]=0; }
    __syncthreads();
    const int* eib = ei + g*2*E_;
    int e0 = b*EPB_;
    for (int e=e0+tid; e<e0+EPB_; e+=1024){
        int s = eib[e], d = eib[E_+e];
        float w = loadf(ew, (long)g*E_+e, isf32);
        atomicAdd(&wdo[s], w); atomicAdd(&wdi[d], w);
        atomicAdd(&co[s], 1);  atomicAdd(&ci[d], 1);
    }
    __syncthreads();
    float* Pdo = part + (size_t)(0*G_ + g)*NBLK_*N_ + (size_t)b*N_;
    float* Pdi = part + (size_t)(1*G_ + g)*NBLK_*N_ + (size_t)b*N_;
    int*   Pci = (int*)part + (size_t)(2*G_ + g)*NBLK_*N_ + (size_t)b*N_;
    int*   Pco = (int*)part + (size_t)(3*G_ + g)*NBLK_*N_ + (size_t)b*N_;
    for (int i=tid;i<N_;i+=1024){
        Pdo[i] = wdo[i]; Pdi[i] = wdi[i];
        Pci[i] = ci[i];  Pco[i] = co[i];
    }
}

// ---------------- reduce partials -> deg/cnt; counts -> per-block exclusive prefix ----------------
__global__ __launch_bounds__(256) void reduce_hist(
        float* __restrict__ part,
        float* __restrict__ deg_o, float* __restrict__ deg_i,
        int* __restrict__ cnt_in, int* __restrict__ cnt_out){
    int g = blockIdx.x >> 4;
    int n = (blockIdx.x & 15)*256 + threadIdx.x;
    if (n >= N_) return;
    float* Pdo = part + (size_t)(0*G_ + g)*NBLK_*N_;
    float* Pdi = part + (size_t)(1*G_ + g)*NBLK_*N_;
    int*   Pci = (int*)part + (size_t)(2*G_ + g)*NBLK_*N_;
    int*   Pco = (int*)part + (size_t)(3*G_ + g)*NBLK_*N_;
    float sdo = 0.f, sdi = 0.f;
    int sci = 0, sco = 0;
    #pragma unroll
    for (int b=0;b<NBLK_;b++){
        size_t idx = (size_t)b*N_ + n;
        sdo += Pdo[idx]; sdi += Pdi[idx];
        int vi = Pci[idx], vo = Pco[idx];
        Pci[idx] = sci;  Pco[idx] = sco;   // exclusive prefix for fill
        sci += vi; sco += vo;
    }
    deg_o[g*N_+n] = sdo; deg_i[g*N_+n] = sdi;
    cnt_in[g*N_+n] = sci; cnt_out[g*N_+n] = sco;
}

// ---------------- exclusive scan -> row_ptr ----------------
__global__ __launch_bounds__(256) void scan_kernel(
        const int* __restrict__ cnt_in, const int* __restrict__ cnt_out,
        int* __restrict__ rp_in, int* __restrict__ rp_out){
    __shared__ int part[256], pref[256];
    int g = blockIdx.x & 31, dir = blockIdx.x >> 5;
    const int* cnt = (dir ? cnt_out : cnt_in) + g*N_;
    int* rp  = (dir ? rp_out  : rp_in)  + g*(N_+1);
    int tid = threadIdx.x, base = tid*16;
    int sum = 0;
    for (int i=0;i<16;i++){ int p = base+i; if (p < N_) sum += cnt[p]; }
    part[tid] = sum;
    __syncthreads();
    if (tid == 0){ int run = 0; for (int j=0;j<256;j++){ pref[j] = run; run += part[j]; } }
    __syncthreads();
    int run = pref[tid];
    for (int i=0;i<16;i++){
        int p = base+i;
        if (p < N_){ rp[p] = run; run += cnt[p]; }
    }
    if (tid == 255) rp[N_] = run;
}

// ---------------- fill CSR (no global atomics) ----------------
__global__ __launch_bounds__(1024) void fill_kernel(
        const int* __restrict__ ei, const void* __restrict__ ew,
        const int* __restrict__ flag,
        const float* __restrict__ deg_o, const float* __restrict__ deg_i,
        const int* __restrict__ rp_in, const int* __restrict__ rp_out,
        const float* __restrict__ part,
        int2* __restrict__ csr_in, int2* __restrict__ csr_out){
    __shared__ int lci[N_], lco[N_];
    int xcd  = blockIdx.x & 7;
    int r2   = blockIdx.x >> 3;
    int g    = xcd*4 + (r2 & 3);
    int b    = r2 >> 2;
    int tid  = threadIdx.x;
    int isf32 = flag[0];
    for (int i=tid;i<N_;i+=1024){ lci[i]=0; lco[i]=0; }
    __syncthreads();
    const int* eib = ei + g*2*E_;
    const int* cumI = (const int*)part + (size_t)(2*G_ + g)*NBLK_*N_ + (size_t)b*N_;
    const int* cumO = (const int*)part + (size_t)(3*G_ + g)*NBLK_*N_ + (size_t)b*N_;
    const int* rpi = rp_in  + g*(N_+1);
    const int* rpo = rp_out + g*(N_+1);
    int2* ci = csr_in  + (long)g*E_;
    int2* co = csr_out + (long)g*E_;
    int e0 = b*EPB_;
    for (int e=e0+tid; e<e0+EPB_; e+=1024){
        int s = eib[e], d = eib[E_+e];
        float dout = deg_o[g*N_+s], din = deg_i[g*N_+d];
        float io = dout > 0.f ? rsqrtf(fmaxf(dout, 1e-12f)) : 0.f;
        float ii = din  > 0.f ? rsqrtf(fmaxf(din , 1e-12f)) : 0.f;
        float nrm = loadf(ew, (long)g*E_ + e, isf32) * io * ii;
        int li = atomicAdd(&lci[d], 1);
        ci[rpi[d] + cumI[d] + li] = make_int2(s, __float_as_int(nrm));
        int lo = atomicAdd(&lco[s], 1);
        co[rpo[s] + cumO[s] + lo] = make_int2(d, __float_as_int(nrm));
    }
}

// ---------------- gather layer 0 -> PQ0 bf16 [GN][128] ----------------
__global__ __launch_bounds__(256) void gather64(
        const int* __restrict__ rp_in, const int* __restrict__ rp_out,
        const int2* __restrict__ csr_in, const int2* __restrict__ csr_out,
        const unsigned short* __restrict__ Xb,
        unsigned short* __restrict__ PQ0){
    int xcd  = blockIdx.x & 7;
    int rest = blockIdx.x >> 3;            // 0..999
    int g    = xcd*4 + (rest & 3);         // wave-uniform
    int chunk= rest >> 2;                  // 0..249
    int wave = threadIdx.x >> 6;
    int lane = threadIdx.x & 63;
    int sub  = lane >> 3;                  // node slot 0..7
    int li   = lane & 7;                   // col group (8 bf16 each)
    int wl   = chunk*32 + wave*8 + sub;    // 0..7999
    int dir  = wl >= N_;  int n = wl - dir*N_;
    const int*  rp  = (dir ? rp_out : rp_in) + g*(N_+1);
    const int2* csr = (dir ? csr_out : csr_in) + (long)g*E_;
    int pb = rp[n], pe = rp[n+1];
    int plast = max(pe - 1, 0);
    const unsigned short* base = Xb + (size_t)g*N_*64;   // scalar base
    float acc[8];
    #pragma unroll
    for (int j=0;j<8;j++) acc[j] = 0.f;
    for (int p = pb; __any(p < pe); p += 4){
        float w[4]; ushort8 v[4];
        #pragma unroll
        for (int i=0;i<4;i++){
            int pi = p+i;
            int2 ent = csr[min(pi, plast)];
            w[i] = (pi < pe) ? __int_as_float(ent.y) : 0.f;
            v[i] = *(const ushort8*)(base + ent.x*64 + li*8);
        }
        #pragma unroll
        for (int i=0;i<4;i++)
            #pragma unroll
            for (int j=0;j<8;j++)
                acc[j] += w[i]*bfu2f(v[i][j]);
    }
    ushort8 o;
    #pragma unroll
    for (int j=0;j<8;j++) o[j] = f2bfu(acc[j]);
    *(ushort8*)(PQ0 + (size_t)(g*N_+n)*128 + dir*64 + li*8) = o;
}

// ---------------- gather layer 1 -> X2 bf16 [GN][256] (XCD-swizzled) ----------------
__global__ __launch_bounds__(256) void gather128(
        const int* __restrict__ rp_in, const int* __restrict__ rp_out,
        const int2* __restrict__ csr_in, const int2* __restrict__ csr_out,
        const unsigned short* __restrict__ hb,
        unsigned short* __restrict__ X2){
    int xcd  = blockIdx.x & 7;
    int rest = blockIdx.x >> 3;            // 0..1999
    int g    = xcd*4 + (rest & 3);         // wave-uniform
    int chunk= rest >> 2;                  // 0..499
    int wave = threadIdx.x >> 6;
    int lane = threadIdx.x & 63;
    int sub  = lane >> 4;                  // node slot 0..3
    int li   = lane & 15;                  // col group (8 bf16 each)
    int wl   = chunk*16 + wave*4 + sub;    // 0..7999
    int dir  = wl >= N_;  int n = wl - dir*N_;
    const int*  rp  = (dir ? rp_out : rp_in) + g*(N_+1);
    const int2* csr = (dir ? csr_out : csr_in) + (long)g*E_;
    int pb = rp[n], pe = rp[n+1];
    int plast = max(pe - 1, 0);
    const unsigned short* base = hb + (size_t)g*N_*128;  // scalar base
    float acc[8];
    #pragma unroll
    for (int j=0;j<8;j++) acc[j] = 0.f;
    for (int p = pb; __any(p < pe); p += 4){
        float w[4]; ushort8 v[4];
        #pragma unroll
        for (int i=0;i<4;i++){
            int pi = p+i;
            int2 ent = csr[min(pi, plast)];
            w[i] = (pi < pe) ? __int_as_float(ent.y) : 0.f;
            v[i] = *(const ushort8*)(base + ent.x*128 + li*8);
        }
        #pragma unroll
        for (int i=0;i<4;i++)
            #pragma unroll
            for (int j=0;j<8;j++)
                acc[j] += w[i]*bfu2f(v[i][j]);
    }
    ushort8 o;
    #pragma unroll
    for (int j=0;j<8;j++) o[j] = f2bfu(acc[j]);
    *(ushort8*)(X2 + (size_t)(g*N_+n)*256 + dir*128 + li*8) = o;
}

// ---------------- MFMA layer-0 GEMM: Hb[GN][128] = PQ0 @ Wc0^T + 0.5(b0s+b0d) ----------------
__global__ __launch_bounds__(256) void gemm0(
        const unsigned short* __restrict__ PQ0, const unsigned short* __restrict__ wc0,
        const float* __restrict__ wcv, __hip_bfloat16* __restrict__ Hb){
    __shared__ unsigned short As[2][64*40];
    int tid  = threadIdx.x;
    int wave = tid >> 6, lane = tid & 63;
    int quad = lane >> 4, l16 = lane & 15;
    int nb = blockIdx.x & 1, mb = blockIdx.x >> 1;
    int m0 = mb*64;
    int col = nb*64 + wave*16 + l16;
    bf16x8 bq[4];
    #pragma unroll
    for (int ks=0; ks<4; ks++)
        bq[ks] = *(const bf16x8*)(wc0 + (size_t)col*128 + ks*32 + quad*8);
    f32x4 acc[4];
    #pragma unroll
    for (int t=0;t<4;t++) acc[t] = (f32x4){0.f,0.f,0.f,0.f};
    int srow = tid>>2, sch = tid&3;
    const unsigned short* src_base = PQ0 + (size_t)(m0 + srow)*128 + sch*8;
    *(float4*)(&As[0][srow*40 + sch*8]) = *(const float4*)(src_base);
    __syncthreads();
    for (int ks=0; ks<4; ks++){
        if (ks < 3)
            *(float4*)(&As[(ks+1)&1][srow*40 + sch*8]) = *(const float4*)(src_base + (ks+1)*32);
        const unsigned short* ab = As[ks&1];
        #pragma unroll
        for (int t=0;t<4;t++){
            bf16x8 a = *(const bf16x8*)(ab + (t*16 + l16)*40 + quad*8);
            acc[t] = __builtin_amdgcn_mfma_f32_16x16x32_bf16(a, bq[ks], acc[t], 0, 0, 0);
        }
        __syncthreads();
    }
    float bias = 0.5f*(wcv[OFF_B0S+col] + wcv[OFF_B0D+col]);
    #pragma unroll
    for (int t=0;t<4;t++){
        #pragma unroll
        for (int r=0;r<4;r++){
            int grow = m0 + t*16 + quad*4 + r;
            Hb[(size_t)grow*128 + col] = __float2bfloat16(acc[t][r] + bias);
        }
    }
}

// ---------------- MFMA gates GEMM: gates3[8000][512][8] = X2 @ Wc^T + biasc ----------------
// R6: epilogue writes step-innermost layout so lstm7 can vector-load 8 steps at once.
__global__ __launch_bounds__(256) void gemmg(
        const unsigned short* __restrict__ X2, const unsigned short* __restrict__ wpc,
        const float* __restrict__ biasc, unsigned short* __restrict__ gates, int gn_base){
    __shared__ unsigned short As[2][64*40];
    int tid  = threadIdx.x;
    int wave = tid >> 6, lane = tid & 63;
    int quad = lane >> 4, l16 = lane & 15;
    int nb = blockIdx.x & 7, mb = blockIdx.x >> 3;
    int m0 = mb*64;
    int col = nb*64 + wave*16 + l16;
    bf16x8 bq[8];
    #pragma unroll
    for (int ks=0; ks<8; ks++)
        bq[ks] = *(const bf16x8*)(wpc + (size_t)col*256 + ks*32 + quad*8);
    f32x4 acc[4];
    #pragma unroll
    for (int t=0;t<4;t++) acc[t] = (f32x4){0.f,0.f,0.f,0.f};
    int srow = tid>>2, sch = tid&3;
    const unsigned short* src_base = X2 + (size_t)(gn_base + m0 + srow)*256 + sch*8;
    *(float4*)(&As[0][srow*40 + sch*8]) = *(const float4*)(src_base);
    __syncthreads();
    for (int ks=0; ks<8; ks++){
        if (ks < 7)
            *(float4*)(&As[(ks+1)&1][srow*40 + sch*8]) = *(const float4*)(src_base + (ks+1)*32);
        const unsigned short* ab = As[ks&1];
        #pragma unroll
        for (int t=0;t<4;t++){
            bf16x8 a = *(const bf16x8*)(ab + (t*16 + l16)*40 + quad*8);
            acc[t] = __builtin_amdgcn_mfma_f32_16x16x32_bf16(a, bq[ks], acc[t], 0, 0, 0);
        }
        __syncthreads();
    }
    float bc = biasc[col];
    #pragma unroll
    for (int t=0;t<4;t++){
        #pragma unroll
        for (int r=0;r<4;r++){
            int grow = m0 + t*16 + quad*4 + r;        // gl = m*8 + step (within half)
            gates[(size_t)(grow>>3)*4096 + (size_t)col*8 + (grow&7)] = f2bfu(acc[t][r] + bc);
        }
    }
}

// ---------------- MFMA recurrent LSTM (8 steps) + projection ----------------
// R6: all 64 gate values (4 groups x 4 rows x 8 steps) prefetched via 16 coalesced
// ushort8 loads before the loop; step loop fully unrolled (compile-time vector index,
// rule #20). Loop body is pure LDS+MFMA+VALU -> no per-step global latency.
__global__ __launch_bounds__(512) void lstm7(
        const unsigned short* __restrict__ gates3, int mbase,
        const unsigned short* __restrict__ whb,
        const float* __restrict__ wcv, const int* __restrict__ flag,
        void* __restrict__ out){
    __shared__ unsigned short hsh[16*136];
    int tid  = threadIdx.x;
    int w    = tid >> 6;
    int lane = tid & 63;
    int quad = lane >> 4, l15 = lane & 15;
    int mlb  = blockIdx.x * 16;          // row base within half
    int m0   = mbase + mlb;              // global row base (output)
    int isf32 = flag[0];

    // prefetch gates: pg[g][r] = all 8 steps for (row mlb+quad*4+r, col g*128+w*16+l15)
    ushort8 pg[4][4];
    const unsigned short* gb = gates3 + (size_t)mlb*4096 + (size_t)(w*16 + l15)*8;
    #pragma unroll
    for (int g=0; g<4; g++)
        #pragma unroll
        for (int r=0; r<4; r++)
            pg[g][r] = *(const ushort8*)(gb + (size_t)(quad*4+r)*4096 + (size_t)g*1024);

    bf16x8 bfrag[4][4];
    #pragma unroll
    for (int g=0; g<4; g++)
        #pragma unroll
        for (int kt=0; kt<4; kt++)
            bfrag[g][kt] = *(const bf16x8*)(whb + (size_t)(g*128 + w*16 + l15)*128 + kt*32 + quad*8);

    for (int t=tid; t<16*136; t+=512) hsh[t] = 0;
    f32x4 c = (f32x4){0.f,0.f,0.f,0.f};
    __syncthreads();

    #pragma unroll
    for (int step=0; step<8; step++){
        f32x4 acc[4];
        #pragma unroll
        for (int g=0; g<4; g++)
            #pragma unroll
            for (int r=0; r<4; r++)
                acc[g][r] = bfu2f(pg[g][r][step]);
        #pragma unroll
        for (int kt=0; kt<4; kt++){
            bf16x8 a = *(const bf16x8*)(hsh + l15*136 + kt*32 + quad*8);
            #pragma unroll
            for (int g=0; g<4; g++)
                acc[g] = __builtin_amdgcn_mfma_f32_16x16x32_bf16(a, bfrag[g][kt], acc[g], 0, 0, 0);
        }
        float hnew[4];
        #pragma unroll
        for (int r=0; r<4; r++){
            float gi = sigmf(acc[0][r]), gf = sigmf(acc[1][r]);
            float gg = tanhfast(acc[2][r]), go = sigmf(acc[3][r]);
            float cc = gf*c[r] + gi*gg;
            c[r] = cc;
            hnew[r] = go*tanhfast(cc);
        }
        __syncthreads();
        #pragma unroll
        for (int r=0; r<4; r++)
            hsh[(quad*4+r)*136 + w*16 + l15] = f2bfu(hnew[r]);
        __syncthreads();
    }
    int r  = tid >> 5;
    int q0 = (tid & 31) * 2;
    float p0 = wcv[OFF_BP + q0], p1 = wcv[OFF_BP + q0 + 1];
    for (int k4=0;k4<32;k4++){
        float4 hv = cvtbf4(*(const ushort4*)(hsh + r*136 + k4*4));
        float4 w0 = *(const float4*)(wcv + OFF_WP + q0*128 + k4*4);
        float4 w1 = *(const float4*)(wcv + OFF_WP + (q0+1)*128 + k4*4);
        p0 += w0.x*hv.x + w0.y*hv.y + w0.z*hv.z + w0.w*hv.w;
        p1 += w1.x*hv.x + w1.y*hv.y + w1.z*hv.z + w1.w*hv.w;
    }
    long o = (long)(m0+r)*64 + q0;
    if (isf32){ ((float*)out)[o] = p0; ((float*)out)[o+1] = p1; }
    else { ((__hip_bfloat16*)out)[o] = __float2bfloat16(p0);
           ((__hip_bfloat16*)out)[o+1] = __float2bfloat16(p1); }
}

extern "C" void kernel_launch(void* const* d_in, const int* in_sizes, int n_in,
                              void* d_out, int out_size, void* d_ws, size_t ws_size,
                              hipStream_t stream){
    const void* x_seq      = d_in[0];
    const int*  edge_index = (const int*)d_in[1];
    const void* edge_weight= d_in[2];

    float* ws    = (float*)d_ws;
    int*   flag  = (int*)(ws + WS_FLAG);
    float* wcv   = ws + WS_WCV;
    unsigned short* whb = (unsigned short*)(ws + WS_WPH);
    unsigned short* wpc = (unsigned short*)(ws + WS_WPC);
    unsigned short* wc0 = (unsigned short*)(ws + WS_WC0);
    float* biasc = ws + WS_BIASC;
    float* deg_o = ws + WS_DEGO;
    float* deg_i = ws + WS_DEGI;
    int*   cnt_i = (int*)(ws + WS_CNTI);
    int*   cnt_o = (int*)(ws + WS_CNTO);
    int*   rp_i  = (int*)(ws + WS_RPI);
    int*   rp_o  = (int*)(ws + WS_RPO);
    float* partb = ws + WS_PART;
    int2*  csr_i = (int2*)(ws + WS_CSRI);
    int2*  csr_o = (int2*)(ws + WS_CSRO);
    unsigned short* X2 = (unsigned short*)(ws + WS_X2);
    unsigned short* Xb = X2;             // aliases X2 (dead once gather128 writes X2)
    __hip_bfloat16* Hb = (__hip_bfloat16*)(ws + WS_HB);
    unsigned short* GT = (unsigned short*)(ws + WS_GT);
    unsigned short* PQ0 = GT;            // aliases GT (dead before gates written)

    sniff_kernel<<<1, 256, 0, stream>>>((const unsigned int*)edge_weight, flag);
    WDesc wd;
    wd.seg[0]  = { d_in[3],  OFF_W0S, 8192  };
    wd.seg[1]  = { d_in[4],  OFF_B0S, 128   };
    wd.seg[2]  = { d_in[5],  OFF_W0D, 8192  };
    wd.seg[3]  = { d_in[6],  OFF_B0D, 128   };
    wd.seg[4]  = { d_in[7],  OFF_W1S, 16384 };
    wd.seg[5]  = { d_in[8],  OFF_B1S, 128   };
    wd.seg[6]  = { d_in[9],  OFF_W1D, 16384 };
    wd.seg[7]  = { d_in[10], OFF_B1D, 128   };
    wd.seg[8]  = { d_in[11], OFF_WIH, 65536 };
    wd.seg[9]  = { d_in[12], OFF_WHH, 65536 };
    wd.seg[10] = { d_in[13], OFF_BIH, 512   };
    wd.seg[11] = { d_in[14], OFF_BHH, 512   };
    wd.seg[12] = { d_in[15], OFF_WP,  8192  };
    wd.seg[13] = { d_in[16], OFF_BP,  64    };
    convert_weights<<<(WCV_TOTAL+255)/256, 256, 0, stream>>>(wd, wcv, flag);
    repack_whh<<<256, 256, 0, stream>>>(wcv, whb);
    repack_wc0<<<64, 256, 0, stream>>>(wcv, wc0);
    compose_wc<<<512, 256, 0, stream>>>(wcv, wpc);
    compose_bias<<<2, 256, 0, stream>>>(wcv, biasc);
    xcvt_kernel<<<(GN_*64+255)/256, 256, 0, stream>>>(x_seq, flag, Xb);

    hist_kernel<<<G_*NBLK_, 1024, 0, stream>>>(edge_index, edge_weight, flag, partb);
    reduce_hist<<<G_*16, 256, 0, stream>>>(partb, deg_o, deg_i, cnt_i, cnt_o);
    scan_kernel<<<64, 256, 0, stream>>>(cnt_i, cnt_o, rp_i, rp_o);
    fill_kernel<<<G_*NBLK_, 1024, 0, stream>>>(edge_index, edge_weight, flag,
                                               deg_o, deg_i, rp_i, rp_o, partb, csr_i, csr_o);

    // layer 0: gather (bf16 Xb, XCD-swizzled, 8 nodes/wave) -> PQ0 bf16 ; MFMA GEMM -> Hb (bf16)
    gather64<<<2*G_*N_/32, 256, 0, stream>>>(rp_i, rp_o, csr_i, csr_o, Xb, PQ0);
    gemm0<<<2*(GN_/64), 256, 0, stream>>>(PQ0, wc0, wcv, Hb);

    // layer 1: gather (XCD-swizzled, 4 nodes/wave) -> X2 (overwrites Xb); per-half: MFMA gates + MFMA LSTM
    gather128<<<2*G_*N_/16, 256, 0, stream>>>(rp_i, rp_o, csr_i, csr_o,
                                              (const unsigned short*)Hb, X2);

    gemmg<<<8*(HALF_GN/64), 256, 0, stream>>>(X2, wpc, biasc, GT, 0);
    lstm7<<<HALF_M/16, 512, 0, stream>>>(GT, 0, whb, wcv, flag, d_out);

    gemmg<<<8*(HALF_GN/64), 256, 0, stream>>>(X2, wpc, biasc, GT, HALF_GN);
    lstm7<<<HALF_M/16, 512, 0, stream>>>(GT, HALF_M, whb, wcv, flag, d_out);
}

// Round 7
// 513.336 us; speedup vs baseline: 1.4718x; 1.0727x over previous
//
#include <hip/hip_runtime.h>
#include <hip/hip_bf16.h>

// Problem constants (B,S,N,F,H,E) = (4,8,4000,64,128,32000)
#define B_  4
#define S_  8
#define N_  4000
#define F_  64
#define H_  128
#define E_  32000
#define G_  (B_*S_)        // 32 graphs
#define GN_ (G_*N_)        // 128000 node rows
#define M_  (B_*N_)        // 16000 LSTM rows
#define GE_ (G_*E_)        // 1,024,000 edges total
#define HALF_GN 64000
#define HALF_M  8000
#define NBLK_   8          // hist/fill blocks per graph
#define EPB_    (E_/NBLK_) // 4000 edges per block

// f32 weight scratch offsets (floats)
#define OFF_W0S 0
#define OFF_B0S 8192
#define OFF_W0D 8320
#define OFF_B0D 16512
#define OFF_W1S 16640
#define OFF_B1S 33024
#define OFF_W1D 33152
#define OFF_B1D 49536
#define OFF_WIH 49664
#define OFF_WHH 115200
#define OFF_BIH 180736
#define OFF_BHH 181248
#define OFF_WP  181760
#define OFF_BP  189952
#define WCV_TOTAL 190016

// workspace layout (float offsets)
#define WS_FLAG   0
#define WS_WCV    16
#define WS_WPH    190032      // Whh bf16 [512][128]: 65536 ushorts
#define WS_WPC    222800      // composed Wc bf16 [512][256]: 131072 ushorts
#define WS_BIASC  288336      // 512 f32
#define WS_DEGO   288848      // deg_o, deg_i, cnt_i, cnt_o contiguous: 4 x 128000 words
#define WS_DEGI   416848
#define WS_CNTI   544848
#define WS_CNTO   672848
#define WS_RPI    800848      // 32*4001
#define WS_RPO    928880
#define WS_CSRI   1312912     // int2 x GE
#define WS_CSRO   3360912
#define WS_X2     5408912     // Xb [GN][64] bf16 (16.4M ushorts)
#define WS_PART   9608912     // hist partials 4 x [32][8][4000] words = 4,096,000 floats
#define WS_HB     21792912    // [GN][128] bf16
#define WS_GT     29984912    // gates3 half [8000][512][8] bf16
#define WS_WC0    46368912    // Wc0 bf16 [128][128]: 16384 ushorts = 8192 floats
// end: 46,377,104 floats = 185.5 MiB (proven budget >= 193 MiB)

typedef __attribute__((ext_vector_type(8))) short bf16x8;
typedef __attribute__((ext_vector_type(4))) float f32x4;
typedef __attribute__((ext_vector_type(8))) unsigned short ushort8;

__device__ inline float bfu2f(unsigned short u){ union{unsigned int i; float f;} v; v.i=((unsigned int)u)<<16; return v.f; }
__device__ inline unsigned short f2bfu(float f){ __hip_bfloat16 b = __float2bfloat16(f); return *(unsigned short*)&b; }
__device__ inline float rcpf(float x){ return __builtin_amdgcn_rcpf(x); }
__device__ inline float sigmf(float x){ return rcpf(1.0f + __expf(-x)); }
__device__ inline float tanhfast(float x){ return 1.0f - 2.0f*rcpf(1.0f + __expf(2.0f*x)); }
__device__ inline float loadf(const void* p, long i, int isf32){
    return isf32 ? ((const float*)p)[i]
                 : __bfloat162float(((const __hip_bfloat16*)p)[i]);
}
__device__ inline float4 cvtbf4(ushort4 u){
    float4 f;
    f.x = __uint_as_float(((unsigned)u.x)<<16);
    f.y = __uint_as_float(((unsigned)u.y)<<16);
    f.z = __uint_as_float(((unsigned)u.z)<<16);
    f.w = __uint_as_float(((unsigned)u.w)<<16);
    return f;
}

// ---------------- dtype sniff (inputs f32 vs bf16) ----------------
__global__ void sniff_kernel(const unsigned int* __restrict__ ew, int* __restrict__ flag){
    __shared__ int s;
    if (threadIdx.x == 0) s = 0;
    __syncthreads();
    unsigned int lo = ew[threadIdx.x] & 0xFFFFu;
    if (lo > 0x3F80u) atomicOr(&s, 1);
    __syncthreads();
    if (threadIdx.x == 0) flag[0] = s;   // 1 => inputs are f32
}

// ---------------- weight conversion to f32 scratch ----------------
struct WSeg { const void* src; int base; int n; };
struct WDesc { WSeg seg[14]; };
__global__ void convert_weights(WDesc d, float* __restrict__ dst, const int* __restrict__ flag){
    int isf32 = flag[0];
    int idx = blockIdx.x*256 + threadIdx.x;
    #pragma unroll
    for (int s=0;s<14;s++){
        int off = idx - d.seg[s].base;
        if (off >= 0 && off < d.seg[s].n){
            dst[idx] = loadf(d.seg[s].src, off, isf32);
            return;
        }
    }
}

// ---------------- Whh bf16 copy ----------------
__global__ void repack_whh(const float* __restrict__ wcv, unsigned short* __restrict__ whb){
    int idx = blockIdx.x*256 + threadIdx.x;   // < 65536
    whb[idx] = f2bfu(wcv[OFF_WHH + idx]);
}

// ---------------- layer-0 composed weights: Wc0[n][k] bf16 [128][128] ----------------
__global__ void repack_wc0(const float* __restrict__ wcv, unsigned short* __restrict__ wc0){
    int idx = blockIdx.x*256 + threadIdx.x;   // < 16384
    int k = idx & 127, n = idx >> 7;
    float v = (k < 64) ? 0.5f*wcv[OFF_W0S + n*64 + k] : 0.5f*wcv[OFF_W0D + n*64 + (k-64)];
    wc0[idx] = f2bfu(v);
}

// ---------------- x_seq -> bf16 Xb [GN][64] ----------------
__global__ void xcvt_kernel(const void* __restrict__ x, const int* __restrict__ flag,
                            unsigned short* __restrict__ Xb){
    long idx = (long)blockIdx.x*256 + threadIdx.x;
    if (idx >= (long)GN_*64) return;
    Xb[idx] = f2bfu(loadf(x, idx, flag[0]));
}

// ---------------- composed weights: Wc[n][k] bf16 [512][256] ----------------
__global__ __launch_bounds__(256) void compose_wc(const float* __restrict__ wcv,
                                                  unsigned short* __restrict__ wpc){
    int n = blockIdx.x;        // 512 blocks
    int k = threadIdx.x;       // 256
    const float* wih = wcv + OFF_WIH + n*128;
    const float* w1  = (k < 128) ? (wcv + OFF_W1S + k) : (wcv + OFF_W1D + (k-128));
    float s = 0.f;
    for (int h=0; h<128; h++) s += wih[h] * w1[h*128];
    wpc[n*256 + k] = f2bfu(0.5f * s);
}

// biasc[n] = bih[n]+bhh[n] + sum_h Wih[n][h]*0.5*(b1s[h]+b1d[h])
__global__ void compose_bias(const float* __restrict__ wcv, float* __restrict__ biasc){
    int n = blockIdx.x*256 + threadIdx.x;
    if (n >= 512) return;
    float s = wcv[OFF_BIH+n] + wcv[OFF_BHH+n];
    const float* wih = wcv + OFF_WIH + n*128;
    for (int h=0; h<128; h++) s += wih[h] * 0.5f*(wcv[OFF_B1S+h] + wcv[OFF_B1D+h]);
    biasc[n] = s;
}

// ---------------- histogram: per-(graph, edge-block) LDS partials ----------------
__global__ __launch_bounds__(1024) void hist_kernel(
        const int* __restrict__ ei, const void* __restrict__ ew, const int* __restrict__ flag,
        float* __restrict__ part){
    __shared__ float wdo[N_], wdi[N_];
    __shared__ int   co[N_],  ci[N_];
    int xcd  = blockIdx.x & 7;
    int r2   = blockIdx.x >> 3;
    int g    = xcd*4 + (r2 & 3);
    int b    = r2 >> 2;                     // 0..7
    int tid  = threadIdx.x;
    int isf32 = flag[0];
    for (int i=tid;i<N_;i+=1024){ wdo[i]=0.f; wdi[i]=0.f; co[i]=0; ci[i]=0; }
    __syncthreads();
    const int* eib = ei + g*2*E_;
    int e0 = b*EPB_;
    for (int e=e0+tid; e<e0+EPB_; e+=1024){
        int s = eib[e], d = eib[E_+e];
        float w = loadf(ew, (long)g*E_+e, isf32);
        atomicAdd(&wdo[s], w); atomicAdd(&wdi[d], w);
        atomicAdd(&co[s], 1);  atomicAdd(&ci[d], 1);
    }
    __syncthreads();
    float* Pdo = part + (size_t)(0*G_ + g)*NBLK_*N_ + (size_t)b*N_;
    float* Pdi = part + (size_t)(1*G_ + g)*NBLK_*N_ + (size_t)b*N_;
    int*   Pci = (int*)part + (size_t)(2*G_ + g)*NBLK_*N_ + (size_t)b*N_;
    int*   Pco = (int*)part + (size_t)(3*G_ + g)*NBLK_*N_ + (size_t)b*N_;
    for (int i=tid;i<N_;i+=1024){
        Pdo[i] = wdo[i]; Pdi[i] = wdi[i];
        Pci[i] = ci[i];  Pco[i] = co[i];
    }
}

// ---------------- reduce partials -> deg/cnt; counts -> per-block exclusive prefix ----------------
__global__ __launch_bounds__(256) void reduce_hist(
        float* __restrict__ part,
        float* __restrict__ deg_o, float* __restrict__ deg_i,
        int* __restrict__ cnt_in, int* __restrict__ cnt_out){
    int g = blockIdx.x >> 4;
    int n = (blockIdx.x & 15)*256 + threadIdx.x;
    if (n >= N_) return;
    float* Pdo = part + (size_t)(0*G_ + g)*NBLK_*N_;
    float* Pdi = part + (size_t)(1*G_ + g)*NBLK_*N_;
    int*   Pci = (int*)part + (size_t)(2*G_ + g)*NBLK_*N_;
    int*   Pco = (int*)part + (size_t)(3*G_ + g)*NBLK_*N_;
    float sdo = 0.f, sdi = 0.f;
    int sci = 0, sco = 0;
    #pragma unroll
    for (int b=0;b<NBLK_;b++){
        size_t idx = (size_t)b*N_ + n;
        sdo += Pdo[idx]; sdi += Pdi[idx];
        int vi = Pci[idx], vo = Pco[idx];
        Pci[idx] = sci;  Pco[idx] = sco;   // exclusive prefix for fill
        sci += vi; sco += vo;
    }
    deg_o[g*N_+n] = sdo; deg_i[g*N_+n] = sdi;
    cnt_in[g*N_+n] = sci; cnt_out[g*N_+n] = sco;
}

// ---------------- exclusive scan -> row_ptr ----------------
__global__ __launch_bounds__(256) void scan_kernel(
        const int* __restrict__ cnt_in, const int* __restrict__ cnt_out,
        int* __restrict__ rp_in, int* __restrict__ rp_out){
    __shared__ int part[256], pref[256];
    int g = blockIdx.x & 31, dir = blockIdx.x >> 5;
    const int* cnt = (dir ? cnt_out : cnt_in) + g*N_;
    int* rp  = (dir ? rp_out  : rp_in)  + g*(N_+1);
    int tid = threadIdx.x, base = tid*16;
    int sum = 0;
    for (int i=0;i<16;i++){ int p = base+i; if (p < N_) sum += cnt[p]; }
    part[tid] = sum;
    __syncthreads();
    if (tid == 0){ int run = 0; for (int j=0;j<256;j++){ pref[j] = run; run += part[j]; } }
    __syncthreads();
    int run = pref[tid];
    for (int i=0;i<16;i++){
        int p = base+i;
        if (p < N_){ rp[p] = run; run += cnt[p]; }
    }
    if (tid == 255) rp[N_] = run;
}

// ---------------- fill CSR (no global atomics) ----------------
__global__ __launch_bounds__(1024) void fill_kernel(
        const int* __restrict__ ei, const void* __restrict__ ew,
        const int* __restrict__ flag,
        const float* __restrict__ deg_o, const float* __restrict__ deg_i,
        const int* __restrict__ rp_in, const int* __restrict__ rp_out,
        const float* __restrict__ part,
        int2* __restrict__ csr_in, int2* __restrict__ csr_out){
    __shared__ int lci[N_], lco[N_];
    int xcd  = blockIdx.x & 7;
    int r2   = blockIdx.x >> 3;
    int g    = xcd*4 + (r2 & 3);
    int b    = r2 >> 2;
    int tid  = threadIdx.x;
    int isf32 = flag[0];
    for (int i=tid;i<N_;i+=1024){ lci[i]=0; lco[i]=0; }
    __syncthreads();
    const int* eib = ei + g*2*E_;
    const int* cumI = (const int*)part + (size_t)(2*G_ + g)*NBLK_*N_ + (size_t)b*N_;
    const int* cumO = (const int*)part + (size_t)(3*G_ + g)*NBLK_*N_ + (size_t)b*N_;
    const int* rpi = rp_in  + g*(N_+1);
    const int* rpo = rp_out + g*(N_+1);
    int2* ci = csr_in  + (long)g*E_;
    int2* co = csr_out + (long)g*E_;
    int e0 = b*EPB_;
    for (int e=e0+tid; e<e0+EPB_; e+=1024){
        int s = eib[e], d = eib[E_+e];
        float dout = deg_o[g*N_+s], din = deg_i[g*N_+d];
        float io = dout > 0.f ? rsqrtf(fmaxf(dout, 1e-12f)) : 0.f;
        float ii = din  > 0.f ? rsqrtf(fmaxf(din , 1e-12f)) : 0.f;
        float nrm = loadf(ew, (long)g*E_ + e, isf32) * io * ii;
        int li = atomicAdd(&lci[d], 1);
        ci[rpi[d] + cumI[d] + li] = make_int2(s, __float_as_int(nrm));
        int lo = atomicAdd(&lco[s], 1);
        co[rpo[s] + cumO[s] + lo] = make_int2(d, __float_as_int(nrm));
    }
}

// ---------------- FUSED layer 0: gather(Xb) -> LDS A-tile -> MFMA -> Hb ----------------
// R7: PQ0 intermediate eliminated. Block = 64 rows x 128 cols. Gather phase: 128
// node-dir tasks x 8 lanes (ushort8/lane), divergent edge loop w/ masked unroll-4.
// LDS row stride 136 ushorts (272B = 68 dwords, %32=4 -> 2-way conflict, free).
// XCD swizzle: each XCD owns 16000 contiguous rows = 4 graphs (Xb slice 2MB, L2-fit).
__global__ __launch_bounds__(256) void g0fused(
        const int* __restrict__ rp_in, const int* __restrict__ rp_out,
        const int2* __restrict__ csr_in, const int2* __restrict__ csr_out,
        const unsigned short* __restrict__ Xb, const unsigned short* __restrict__ wc0,
        const float* __restrict__ wcv, __hip_bfloat16* __restrict__ Hb){
    __shared__ unsigned short As[64*136];
    int xcd  = blockIdx.x & 7;
    int tile = blockIdx.x >> 3;            // 0..249
    int m0   = (xcd*250 + tile)*64;        // row base in [0, GN)
    int tid  = threadIdx.x;

    // ---- gather phase ----
    int gid = tid >> 3, li = tid & 7;      // 32 groups x 8 lanes
    #pragma unroll
    for (int t=0; t<4; t++){
        int task = t*32 + gid;             // 0..127
        int dir  = task >> 6, r = task & 63;
        int grow = m0 + r;
        int g = grow / N_;  int n = grow - g*N_;
        const int*  rp  = (dir ? rp_out : rp_in) + g*(N_+1);
        const int2* csr = (dir ? csr_out : csr_in) + (long)g*E_;
        int pb = rp[n], pe = rp[n+1];
        int plast = max(pe - 1, 0);
        const unsigned short* base = Xb + (size_t)g*N_*64;
        float acc[8];
        #pragma unroll
        for (int j=0;j<8;j++) acc[j] = 0.f;
        for (int p=pb; p<pe; p+=4){
            float w4[4]; ushort8 v4[4];
            #pragma unroll
            for (int i=0;i<4;i++){
                int pi = p+i;
                int2 ent = csr[min(pi, plast)];
                w4[i] = (pi < pe) ? __int_as_float(ent.y) : 0.f;
                v4[i] = *(const ushort8*)(base + ent.x*64 + li*8);
            }
            #pragma unroll
            for (int i=0;i<4;i++)
                #pragma unroll
                for (int j=0;j<8;j++)
                    acc[j] += w4[i]*bfu2f(v4[i][j]);
        }
        ushort8 o;
        #pragma unroll
        for (int j=0;j<8;j++) o[j] = f2bfu(acc[j]);
        *(ushort8*)(&As[r*136 + dir*64 + li*8]) = o;
    }
    __syncthreads();

    // ---- GEMM phase: 64 rows x 128 cols, K=128 ----
    int wave = tid >> 6, lane = tid & 63;
    int quad = lane >> 4, l16 = lane & 15;
    int colb = wave*16 + l16;              // 0..63
    bf16x8 bq[2][4];
    f32x4 acc[2][4];
    #pragma unroll
    for (int s=0;s<2;s++){
        #pragma unroll
        for (int ks=0;ks<4;ks++)
            bq[s][ks] = *(const bf16x8*)(wc0 + (size_t)(colb + s*64)*128 + ks*32 + quad*8);
        #pragma unroll
        for (int t=0;t<4;t++) acc[s][t] = (f32x4){0.f,0.f,0.f,0.f};
    }
    #pragma unroll
    for (int ks=0;ks<4;ks++){
        #pragma unroll
        for (int t=0;t<4;t++){
            bf16x8 a = *(const bf16x8*)(&As[(t*16 + l16)*136 + ks*32 + quad*8]);
            acc[0][t] = __builtin_amdgcn_mfma_f32_16x16x32_bf16(a, bq[0][ks], acc[0][t], 0, 0, 0);
            acc[1][t] = __builtin_amdgcn_mfma_f32_16x16x32_bf16(a, bq[1][ks], acc[1][t], 0, 0, 0);
        }
    }
    #pragma unroll
    for (int s=0;s<2;s++){
        int col = colb + s*64;
        float bias = 0.5f*(wcv[OFF_B0S+col] + wcv[OFF_B0D+col]);
        #pragma unroll
        for (int t=0;t<4;t++)
            #pragma unroll
            for (int r=0;r<4;r++)
                Hb[(size_t)(m0 + t*16 + quad*4 + r)*128 + col] = __float2bfloat16(acc[s][t][r] + bias);
    }
}

// ---------------- FUSED layer 1: gather(Hb) -> LDS A-tile -> MFMA -> gates3 ----------------
// R7: X2 intermediate eliminated. Block = 64 rows x 512 cols, 512 threads (8 waves).
// Gather: 128 node-dir tasks x 16 lanes (ushort8). LDS row stride 264 ushorts
// (528B = 132 dwords, %32=4 -> 2-way, free). GEMM: 4 col-passes x (8 waves x 16 cols),
// bq reloaded per pass (wpc is L2-resident). Epilogue keeps gates3 step-innermost.
// XCD swizzle: per half each XCD owns 8000 rows = 2 graphs (Hb slice 2MB, L2-fit).
__global__ __launch_bounds__(512) void ggfused(
        const int* __restrict__ rp_in, const int* __restrict__ rp_out,
        const int2* __restrict__ csr_in, const int2* __restrict__ csr_out,
        const unsigned short* __restrict__ hb,
        const unsigned short* __restrict__ wpc, const float* __restrict__ biasc,
        unsigned short* __restrict__ gates, int gn_base){
    __shared__ unsigned short As[64*264];
    int xcd  = blockIdx.x & 7;
    int tile = blockIdx.x >> 3;            // 0..124
    int m0   = (xcd*125 + tile)*64;        // row base within half
    int tid  = threadIdx.x;

    // ---- gather phase ----
    int gid = tid >> 4, li = tid & 15;     // 32 groups x 16 lanes
    #pragma unroll
    for (int t=0; t<4; t++){
        int task = t*32 + gid;             // 0..127
        int dir  = task >> 6, r = task & 63;
        int grow = gn_base + m0 + r;
        int g = grow / N_;  int n = grow - g*N_;
        const int*  rp  = (dir ? rp_out : rp_in) + g*(N_+1);
        const int2* csr = (dir ? csr_out : csr_in) + (long)g*E_;
        int pb = rp[n], pe = rp[n+1];
        int plast = max(pe - 1, 0);
        const unsigned short* base = hb + (size_t)g*N_*128;
        float acc[8];
        #pragma unroll
        for (int j=0;j<8;j++) acc[j] = 0.f;
        for (int p=pb; p<pe; p+=4){
            float w4[4]; ushort8 v4[4];
            #pragma unroll
            for (int i=0;i<4;i++){
                int pi = p+i;
                int2 ent = csr[min(pi, plast)];
                w4[i] = (pi < pe) ? __int_as_float(ent.y) : 0.f;
                v4[i] = *(const ushort8*)(base + ent.x*128 + li*8);
            }
            #pragma unroll
            for (int i=0;i<4;i++)
                #pragma unroll
                for (int j=0;j<8;j++)
                    acc[j] += w4[i]*bfu2f(v4[i][j]);
        }
        ushort8 o;
        #pragma unroll
        for (int j=0;j<8;j++) o[j] = f2bfu(acc[j]);
        *(ushort8*)(&As[r*264 + dir*128 + li*8]) = o;
    }
    __syncthreads();

    // ---- GEMM phase: 64 rows x 512 cols, K=256, 4 col-passes ----
    int w = tid >> 6, lane = tid & 63;
    int quad = lane >> 4, l16 = lane & 15;
    for (int cs=0; cs<4; cs++){
        int col = cs*128 + w*16 + l16;
        bf16x8 bq[8];
        #pragma unroll
        for (int ks=0;ks<8;ks++)
            bq[ks] = *(const bf16x8*)(wpc + (size_t)col*256 + ks*32 + quad*8);
        f32x4 acc[4];
        #pragma unroll
        for (int t=0;t<4;t++) acc[t] = (f32x4){0.f,0.f,0.f,0.f};
        #pragma unroll
        for (int ks=0;ks<8;ks++)
            #pragma unroll
            for (int t=0;t<4;t++){
                bf16x8 a = *(const bf16x8*)(&As[(t*16 + l16)*264 + ks*32 + quad*8]);
                acc[t] = __builtin_amdgcn_mfma_f32_16x16x32_bf16(a, bq[ks], acc[t], 0, 0, 0);
            }
        float bc = biasc[col];
        #pragma unroll
        for (int t=0;t<4;t++)
            #pragma unroll
            for (int r=0;r<4;r++){
                int grow = m0 + t*16 + quad*4 + r;    // gl = m*8 + step (within half)
                gates[(size_t)(grow>>3)*4096 + (size_t)col*8 + (grow&7)] = f2bfu(acc[t][r] + bc);
            }
    }
}

// ---------------- MFMA recurrent LSTM (8 steps) + projection ----------------
__global__ __launch_bounds__(512) void lstm7(
        const unsigned short* __restrict__ gates3, int mbase,
        const unsigned short* __restrict__ whb,
        const float* __restrict__ wcv, const int* __restrict__ flag,
        void* __restrict__ out){
    __shared__ unsigned short hsh[16*136];
    int tid  = threadIdx.x;
    int w    = tid >> 6;
    int lane = tid & 63;
    int quad = lane >> 4, l15 = lane & 15;
    int mlb  = blockIdx.x * 16;          // row base within half
    int m0   = mbase + mlb;              // global row base (output)
    int isf32 = flag[0];

    ushort8 pg[4][4];
    const unsigned short* gb = gates3 + (size_t)mlb*4096 + (size_t)(w*16 + l15)*8;
    #pragma unroll
    for (int g=0; g<4; g++)
        #pragma unroll
        for (int r=0; r<4; r++)
            pg[g][r] = *(const ushort8*)(gb + (size_t)(quad*4+r)*4096 + (size_t)g*1024);

    bf16x8 bfrag[4][4];
    #pragma unroll
    for (int g=0; g<4; g++)
        #pragma unroll
        for (int kt=0; kt<4; kt++)
            bfrag[g][kt] = *(const bf16x8*)(whb + (size_t)(g*128 + w*16 + l15)*128 + kt*32 + quad*8);

    for (int t=tid; t<16*136; t+=512) hsh[t] = 0;
    f32x4 c = (f32x4){0.f,0.f,0.f,0.f};
    __syncthreads();

    #pragma unroll
    for (int step=0; step<8; step++){
        f32x4 acc[4];
        #pragma unroll
        for (int g=0; g<4; g++)
            #pragma unroll
            for (int r=0; r<4; r++)
                acc[g][r] = bfu2f(pg[g][r][step]);
        #pragma unroll
        for (int kt=0; kt<4; kt++){
            bf16x8 a = *(const bf16x8*)(hsh + l15*136 + kt*32 + quad*8);
            #pragma unroll
            for (int g=0; g<4; g++)
                acc[g] = __builtin_amdgcn_mfma_f32_16x16x32_bf16(a, bfrag[g][kt], acc[g], 0, 0, 0);
        }
        float hnew[4];
        #pragma unroll
        for (int r=0; r<4; r++){
            float gi = sigmf(acc[0][r]), gf = sigmf(acc[1][r]);
            float gg = tanhfast(acc[2][r]), go = sigmf(acc[3][r]);
            float cc = gf*c[r] + gi*gg;
            c[r] = cc;
            hnew[r] = go*tanhfast(cc);
        }
        __syncthreads();
        #pragma unroll
        for (int r=0; r<4; r++)
            hsh[(quad*4+r)*136 + w*16 + l15] = f2bfu(hnew[r]);
        __syncthreads();
    }
    int r  = tid >> 5;
    int q0 = (tid & 31) * 2;
    float p0 = wcv[OFF_BP + q0], p1 = wcv[OFF_BP + q0 + 1];
    for (int k4=0;k4<32;k4++){
        float4 hv = cvtbf4(*(const ushort4*)(hsh + r*136 + k4*4));
        float4 w0 = *(const float4*)(wcv + OFF_WP + q0*128 + k4*4);
        float4 w1 = *(const float4*)(wcv + OFF_WP + (q0+1)*128 + k4*4);
        p0 += w0.x*hv.x + w0.y*hv.y + w0.z*hv.z + w0.w*hv.w;
        p1 += w1.x*hv.x + w1.y*hv.y + w1.z*hv.z + w1.w*hv.w;
    }
    long o = (long)(m0+r)*64 + q0;
    if (isf32){ ((float*)out)[o] = p0; ((float*)out)[o+1] = p1; }
    else { ((__hip_bfloat16*)out)[o] = __float2bfloat16(p0);
           ((__hip_bfloat16*)out)[o+1] = __float2bfloat16(p1); }
}

extern "C" void kernel_launch(void* const* d_in, const int* in_sizes, int n_in,
                              void* d_out, int out_size, void* d_ws, size_t ws_size,
                              hipStream_t stream){
    const void* x_seq      = d_in[0];
    const int*  edge_index = (const int*)d_in[1];
    const void* edge_weight= d_in[2];

    float* ws    = (float*)d_ws;
    int*   flag  = (int*)(ws + WS_FLAG);
    float* wcv   = ws + WS_WCV;
    unsigned short* whb = (unsigned short*)(ws + WS_WPH);
    unsigned short* wpc = (unsigned short*)(ws + WS_WPC);
    unsigned short* wc0 = (unsigned short*)(ws + WS_WC0);
    float* biasc = ws + WS_BIASC;
    float* deg_o = ws + WS_DEGO;
    float* deg_i = ws + WS_DEGI;
    int*   cnt_i = (int*)(ws + WS_CNTI);
    int*   cnt_o = (int*)(ws + WS_CNTO);
    int*   rp_i  = (int*)(ws + WS_RPI);
    int*   rp_o  = (int*)(ws + WS_RPO);
    float* partb = ws + WS_PART;
    int2*  csr_i = (int2*)(ws + WS_CSRI);
    int2*  csr_o = (int2*)(ws + WS_CSRO);
    unsigned short* Xb = (unsigned short*)(ws + WS_X2);
    __hip_bfloat16* Hb = (__hip_bfloat16*)(ws + WS_HB);
    unsigned short* GT = (unsigned short*)(ws + WS_GT);

    sniff_kernel<<<1, 256, 0, stream>>>((const unsigned int*)edge_weight, flag);
    WDesc wd;
    wd.seg[0]  = { d_in[3],  OFF_W0S, 8192  };
    wd.seg[1]  = { d_in[4],  OFF_B0S, 128   };
    wd.seg[2]  = { d_in[5],  OFF_W0D, 8192  };
    wd.seg[3]  = { d_in[6],  OFF_B0D, 128   };
    wd.seg[4]  = { d_in[7],  OFF_W1S, 16384 };
    wd.seg[5]  = { d_in[8],  OFF_B1S, 128   };
    wd.seg[6]  = { d_in[9],  OFF_W1D, 16384 };
    wd.seg[7]  = { d_in[10], OFF_B1D, 128   };
    wd.seg[8]  = { d_in[11], OFF_WIH, 65536 };
    wd.seg[9]  = { d_in[12], OFF_WHH, 65536 };
    wd.seg[10] = { d_in[13], OFF_BIH, 512   };
    wd.seg[11] = { d_in[14], OFF_BHH, 512   };
    wd.seg[12] = { d_in[15], OFF_WP,  8192  };
    wd.seg[13] = { d_in[16], OFF_BP,  64    };
    convert_weights<<<(WCV_TOTAL+255)/256, 256, 0, stream>>>(wd, wcv, flag);
    repack_whh<<<256, 256, 0, stream>>>(wcv, whb);
    repack_wc0<<<64, 256, 0, stream>>>(wcv, wc0);
    compose_wc<<<512, 256, 0, stream>>>(wcv, wpc);
    compose_bias<<<2, 256, 0, stream>>>(wcv, biasc);
    xcvt_kernel<<<(GN_*64+255)/256, 256, 0, stream>>>(x_seq, flag, Xb);

    hist_kernel<<<G_*NBLK_, 1024, 0, stream>>>(edge_index, edge_weight, flag, partb);
    reduce_hist<<<G_*16, 256, 0, stream>>>(partb, deg_o, deg_i, cnt_i, cnt_o);
    scan_kernel<<<64, 256, 0, stream>>>(cnt_i, cnt_o, rp_i, rp_o);
    fill_kernel<<<G_*NBLK_, 1024, 0, stream>>>(edge_index, edge_weight, flag,
                                               deg_o, deg_i, rp_i, rp_o, partb, csr_i, csr_o);

    // layer 0 fused: gather(Xb) + GEMM -> Hb   (PQ0 eliminated)
    g0fused<<<GN_/64, 256, 0, stream>>>(rp_i, rp_o, csr_i, csr_o, Xb, wc0, wcv, Hb);

    // layer 1 fused per half: gather(Hb) + gates GEMM -> GT ; then LSTM
    ggfused<<<HALF_GN/64, 512, 0, stream>>>(rp_i, rp_o, csr_i, csr_o,
                                            (const unsigned short*)Hb, wpc, biasc, GT, 0);
    lstm7<<<HALF_M/16, 512, 0, stream>>>(GT, 0, whb, wcv, flag, d_out);

    ggfused<<<HALF_GN/64, 512, 0, stream>>>(rp_i, rp_o, csr_i, csr_o,
                                            (const unsigned short*)Hb, wpc, biasc, GT, HALF_GN);
    lstm7<<<HALF_M/16, 512, 0, stream>>>(GT, HALF_M, whb, wcv, flag, d_out);
}